// Round 13
// baseline (587.571 us; speedup 1.0000x reference)
//
#include <hip/hip_runtime.h>
#include <math.h>

typedef unsigned short u16;
typedef __attribute__((ext_vector_type(8))) short bf16x8;
typedef __attribute__((ext_vector_type(4))) float f32x4;

__device__ inline u16 f2bf(float x) {
  unsigned int u = __float_as_uint(x);
  u += 0x7fffu + ((u >> 16) & 1u);
  return (u16)(u >> 16);
}
__device__ inline float bf2f(u16 h) {
  return __uint_as_float(((unsigned int)h) << 16);
}
// unpack 8 bf16 (uint4) -> two float4
__device__ inline void cvt8(uint4 v, float4& A, float4& B) {
  A.x = __uint_as_float(v.x << 16);
  A.y = __uint_as_float(v.x & 0xffff0000u);
  A.z = __uint_as_float(v.y << 16);
  A.w = __uint_as_float(v.y & 0xffff0000u);
  B.x = __uint_as_float(v.z << 16);
  B.y = __uint_as_float(v.z & 0xffff0000u);
  B.z = __uint_as_float(v.w << 16);
  B.w = __uint_as_float(v.w & 0xffff0000u);
}
__device__ inline unsigned int pk2bf(float lo, float hi) {
  return (unsigned int)f2bf(lo) | ((unsigned int)f2bf(hi) << 16);
}

// ---------------- setup: zero cnt + weight split + layer-1 linear (fused) ----------------
__global__ void k_setup(int* __restrict__ cnt, int nz,
                        const float* __restrict__ W2pl, const float* __restrict__ W2pr,
                        const float* __restrict__ W2ll, const float* __restrict__ W2lr,
                        u16* __restrict__ Whp, u16* __restrict__ Wlp,
                        u16* __restrict__ Whl, u16* __restrict__ Wll_o,
                        const float* __restrict__ xp, int Kp, int Np,
                        const float* __restrict__ xl_, int Kl, int Nl,
                        const float* __restrict__ W1pl, const float* __restrict__ W1pr,
                        const float* __restrict__ W1ll, const float* __restrict__ W1lr,
                        u16* __restrict__ xlh_p, u16* __restrict__ xrh_p,
                        u16* __restrict__ xlh_l, u16* __restrict__ xrh_l,
                        int linPer) {
  const int zb = (nz + 255) / 256;
  if ((int)blockIdx.x < zb) {
    int i = blockIdx.x * 256 + threadIdx.x;
    if (i < nz) cnt[i] = 0;
    return;
  }
  int wb = blockIdx.x - zb;
  if (wb < 1024) {  // weight split
    int n = wb & 511;
    int side = wb >> 9;
    int col = n & 255;
    int k = threadIdx.x;
    const float* W = side == 0 ? (n < 256 ? W2pl : W2pr) : (n < 256 ? W2ll : W2lr);
    float w = W[k * 256 + col];
    u16* Wh = side ? Whl : Whp;
    u16* Wlo = side ? Wll_o : Wlp;
    u16 hb = f2bf(w);
    Wh[n * 256 + k] = hb;
    Wlo[n * 256 + k] = f2bf(w - bf2f(hb));
    return;
  }
  // layer-1 linear
  int wb2 = wb - 1024;
  const int side = wb2 / linPer;
  const float* x = side ? xl_ : xp;
  const int K = side ? Kl : Kp;
  const int N = side ? Nl : Np;
  const float* Wl = side ? W1ll : W1pl;
  const float* Wr = side ? W1lr : W1pr;
  u16* xlh = side ? xlh_l : xlh_p;
  u16* xrh = side ? xrh_l : xrh_p;
  int base = (wb2 - side * linPer) * 8;
  if (base >= N) return;
  int j = threadIdx.x;
  __shared__ float xs[8][16];
  int tot = 8 * K;
  for (int i = j; i < tot; i += 256) {
    int r = i / K, k = i - r * K;
    if (base + r < N) xs[r][k] = x[(size_t)(base + r) * K + k];
  }
  __syncthreads();
#pragma unroll
  for (int r = 0; r < 8; ++r) {
    int n = base + r;
    if (n >= N) break;
    float al = 0.f, ar = 0.f;
    for (int k = 0; k < K; ++k) {
      float xv = xs[r][k];
      al = fmaf(xv, Wl[k * 256 + j], al);
      ar = fmaf(xv, Wr[k * 256 + j], ar);
    }
    xlh[(size_t)n * 256 + j] = f2bf(al);
    xrh[(size_t)n * 256 + j] = f2bf(ar);
  }
}

// ---------------- histogram (both sides) ----------------
__global__ void k_histb(const int* __restrict__ eip, int Ep, const int* __restrict__ eil,
                        int El, int* __restrict__ cntp, int* __restrict__ cntl) {
  int e = blockIdx.x * blockDim.x + threadIdx.x;
  if (e < Ep) atomicAdd(&cntp[eip[Ep + e]], 1);
  else if (e < Ep + El) { int e2 = e - Ep; atomicAdd(&cntl[eil[El + e2]], 1); }
}

// ---------------- per-block scan (also zeroes cur) ----------------
__global__ void k_scan1b(const int* __restrict__ cntp, int Np, const int* __restrict__ cntl,
                         int Nl, int nbp, int* __restrict__ offsp, int* __restrict__ offsl,
                         int* __restrict__ curp, int* __restrict__ curl,
                         int* __restrict__ bsum) {
  __shared__ int s[256];
  int tid = threadIdx.x;
  int side = ((int)blockIdx.x >= nbp) ? 1 : 0;
  int blk = side ? (blockIdx.x - nbp) : blockIdx.x;
  const int* cnt = side ? cntl : cntp;
  int* offs = side ? offsl : offsp;
  int* cur = side ? curl : curp;
  int N = side ? Nl : Np;
  int i = blk * 256 + tid;
  int v = (i < N) ? cnt[i] : 0;
  if (i < N) cur[i] = 0;
  s[tid] = v;
  __syncthreads();
  for (int off = 1; off < 256; off <<= 1) {
    int t = 0;
    if (tid >= off) t = s[tid - off];
    __syncthreads();
    if (tid >= off) s[tid] += t;
    __syncthreads();
  }
  if (i < N) offs[i] = s[tid] - v;
  if (tid == 255) bsum[side * 256 + blk] = s[255];
}

__global__ void k_scan2b(int* __restrict__ bsum, int nbp, int nbl) {
  __shared__ int s[256];
  int side = blockIdx.x;
  int nb = side ? nbl : nbp;
  int* bs = bsum + side * 256;
  int tid = threadIdx.x;
  int v = (tid < nb) ? bs[tid] : 0;
  s[tid] = v;
  __syncthreads();
  for (int off = 1; off < 256; off <<= 1) {
    int t = 0;
    if (tid >= off) t = s[tid - off];
    __syncthreads();
    if (tid >= off) s[tid] += t;
    __syncthreads();
  }
  if (tid < nb) bs[tid] = s[tid] - v;
}

// ---------------- fill (bsum folded in) ----------------
__global__ void k_fillb(const int* __restrict__ eip, int Ep, const int* __restrict__ eil,
                        int El, const int* __restrict__ offsp, const int* __restrict__ offsl,
                        const int* __restrict__ bsum,
                        int* __restrict__ curp, int* __restrict__ curl,
                        int* __restrict__ csrp, int* __restrict__ csrl) {
  int e = blockIdx.x * blockDim.x + threadIdx.x;
  if (e < Ep) {
    int d = eip[Ep + e];
    int pos = offsp[d] + bsum[d >> 8] + atomicAdd(&curp[d], 1);
    csrp[pos] = eip[e];
  } else if (e < Ep + El) {
    int e2 = e - Ep;
    int d = eil[El + e2];
    int pos = offsl[d] + bsum[256 + (d >> 8)] + atomicAdd(&curl[d], 1);
    csrl[pos] = eil[e2];
  }
}

// ---------------- dual GEMM, 128x128 y=4 proven shape; XCD-grouped block swizzle ----------------
// NOTE: 128x256-wide tile regressed 2x with ~3.6x HBM write amplification (rounds 6, 11).
// Swizzle: the 4 col-tiles sharing an A row-block get ids congruent mod 8 -> same XCD L2.
__global__ void __launch_bounds__(256, 2) k_mm_dual_b(
    const u16* __restrict__ A_p, const u16* __restrict__ A_l,
    const u16* __restrict__ Bh_p, const u16* __restrict__ Bl_p,
    const u16* __restrict__ Bh_l, const u16* __restrict__ Bl_l,
    u16* __restrict__ XLh_p, u16* __restrict__ XRh_p,
    u16* __restrict__ XLh_l, u16* __restrict__ XRh_l, int Np, int Nl, int Rp, int Rtot) {
  __shared__ __align__(16) char smem[32768];
  char* sA = smem;
  char* sBh = smem + 8192;
  char* sBl = smem + 16384;
  const int gid = blockIdx.x;
  const int rblk = (gid >> 5) * 8 + (gid & 7);
  const int col = (gid >> 3) & 3;
  if (rblk >= Rtot) return;
  const int side = (rblk >= Rp) ? 1 : 0;
  const int rloc = side ? rblk - Rp : rblk;
  const u16* A = side ? A_l : A_p;
  const u16* Bhi = side ? Bh_l : Bh_p;
  const u16* Blo = side ? Bl_l : Bl_p;
  u16* XLh = side ? XLh_l : XLh_p;
  u16* XRh = side ? XRh_l : XRh_p;
  const int M = side ? Nl : Np;
  const int t = threadIdx.x;
  const int rowBase = rloc * 128;
  const int j0 = col * 128;
  const int srow = t >> 1;
  const int h = t & 1;
  int gr = rowBase + srow;
  if (gr >= M) gr = M - 1;
  const size_t gaBase = (size_t)gr * 256 + h * 16;
  const size_t gbBase = (size_t)(j0 + srow) * 256 + h * 16;
  const int rb = srow * 64;
  const int sw0 = (((h * 2) + (srow >> 1)) & 3) * 16;
  const int sw1 = (((h * 2 + 1) + (srow >> 1)) & 3) * 16;
  const int lane = t & 63;
  const int wid = t >> 6;
  const int wm = (wid & 1) * 64;
  const int wn = (wid >> 1) * 64;
  const int kq = lane >> 4;
  const int mr = lane & 15;
  int offA[4], offB[4];
#pragma unroll
  for (int i = 0; i < 4; ++i) {
    int m = wm + i * 16 + mr;
    offA[i] = m * 64 + ((kq + (m >> 1)) & 3) * 16;
    int n = wn + i * 16 + mr;
    offB[i] = n * 64 + ((kq + (n >> 1)) & 3) * 16;
  }
  f32x4 acc[4][4] = {};
  for (int kt = 0; kt < 8; ++kt) {
    const int k0 = kt * 32;
    uint4 va0 = *(const uint4*)(A + gaBase + k0);
    uint4 va1 = *(const uint4*)(A + gaBase + k0 + 8);
    uint4 vbh0 = *(const uint4*)(Bhi + gbBase + k0);
    uint4 vbh1 = *(const uint4*)(Bhi + gbBase + k0 + 8);
    uint4 vbl0 = *(const uint4*)(Blo + gbBase + k0);
    uint4 vbl1 = *(const uint4*)(Blo + gbBase + k0 + 8);
    __syncthreads();
    *(uint4*)(sA + rb + sw0) = va0;
    *(uint4*)(sA + rb + sw1) = va1;
    *(uint4*)(sBh + rb + sw0) = vbh0;
    *(uint4*)(sBh + rb + sw1) = vbh1;
    *(uint4*)(sBl + rb + sw0) = vbl0;
    *(uint4*)(sBl + rb + sw1) = vbl1;
    __syncthreads();
    bf16x8 a[4], bh[4], bl[4];
#pragma unroll
    for (int i = 0; i < 4; ++i) {
      a[i] = *(const bf16x8*)(sA + offA[i]);
      bh[i] = *(const bf16x8*)(sBh + offB[i]);
      bl[i] = *(const bf16x8*)(sBl + offB[i]);
    }
#pragma unroll
    for (int i = 0; i < 4; ++i)
#pragma unroll
      for (int j = 0; j < 4; ++j) {
        acc[i][j] = __builtin_amdgcn_mfma_f32_16x16x32_bf16(a[i], bh[j], acc[i][j], 0, 0, 0);
        acc[i][j] = __builtin_amdgcn_mfma_f32_16x16x32_bf16(a[i], bl[j], acc[i][j], 0, 0, 0);
      }
  }
  __syncthreads();
  u16* wtile = (u16*)(smem + wid * 8192);
#pragma unroll
  for (int i = 0; i < 4; ++i)
#pragma unroll
    for (int j = 0; j < 4; ++j)
#pragma unroll
      for (int r = 0; r < 4; ++r)
        wtile[(i * 16 + kq * 4 + r) * 64 + j * 16 + mr] = f2bf(acc[i][j][r]);
  u16* cbase = (col < 2) ? XLh : XRh;
  const int cb = (col < 2) ? j0 : j0 - 256;
  const int r8 = lane >> 3;
  const int c8 = lane & 7;
#pragma unroll
  for (int rr = 0; rr < 8; ++rr) {
    int lr = rr * 8 + r8;
    uint4 v = *(const uint4*)&wtile[lr * 64 + c8 * 8];
    int row = rowBase + wm + lr;
    if (row < M) *(uint4*)&cbase[(size_t)row * 256 + cb + wn + c8 * 8] = v;
  }
}

// ---------------- GATv2 aggregation: two half-waves (32 lanes x 8 ch) per dst ----------------
// lrelu(t)*wa == t*(0.6wa) + |t|*(0.4wa) exactly; softmax shift fixed at self logit.
#define DOT8(A0, A1, q)                                                       \
  {                                                                           \
    float t;                                                                  \
    t = A0.x + rd0.x; q = fmaf(t, s60.x, fabsf(t) * s40.x);                   \
    t = A0.y + rd0.y; q = fmaf(fabsf(t), s40.y, fmaf(t, s60.y, q));           \
    t = A0.z + rd0.z; q = fmaf(fabsf(t), s40.z, fmaf(t, s60.z, q));           \
    t = A0.w + rd0.w; q = fmaf(fabsf(t), s40.w, fmaf(t, s60.w, q));           \
    t = A1.x + rd1.x; q = fmaf(fabsf(t), s41.x, fmaf(t, s61.x, q));           \
    t = A1.y + rd1.y; q = fmaf(fabsf(t), s41.y, fmaf(t, s61.y, q));           \
    t = A1.z + rd1.z; q = fmaf(fabsf(t), s41.z, fmaf(t, s61.z, q));           \
    t = A1.w + rd1.w; q = fmaf(fabsf(t), s41.w, fmaf(t, s61.w, q));           \
  }

#define RED(q)                                                                \
  {                                                                           \
    _Pragma("unroll")                                                         \
    for (int off = 1; off <= (H == 2 ? 8 : 16); off <<= 1)                    \
      q += __shfl_xor(q, off, 64);                                            \
  }

template <int H>
__global__ void k_gat_gather_b(
    const u16* __restrict__ xlh_p, const u16* __restrict__ xrh_p, u16* __restrict__ out_p,
    const u16* __restrict__ xlh_l, const u16* __restrict__ xrh_l, u16* __restrict__ out_l,
    const int* __restrict__ csr_p, const int* __restrict__ offs_p,
    const int* __restrict__ cnt_p,
    const int* __restrict__ csr_l, const int* __restrict__ offs_l,
    const int* __restrict__ cnt_l, const int* __restrict__ bsum,
    const float* __restrict__ att_p, const float* __restrict__ bias_p,
    const float* __restrict__ att_l, const float* __restrict__ bias_l,
    int Np, int Nl) {
  const int side = blockIdx.y;
  const u16* xlh = side ? xlh_l : xlh_p;
  const u16* xrh = side ? xrh_l : xrh_p;
  u16* out = side ? out_l : out_p;
  const int* csr = side ? csr_l : csr_p;
  const int* offs = side ? offs_l : offs_p;
  const int* cnt = side ? cnt_l : cnt_p;
  const float* att = side ? att_l : att_p;
  const float* bias = side ? bias_l : bias_p;
  const int N = side ? Nl : Np;
  int d = blockIdx.x * 4 + (threadIdx.x >> 6);
  if (d >= N) return;
  const int lane = threadIdx.x & 63;
  const int half = lane >> 5;
  const int cb = (lane & 31) * 8;  // channel base, 8 ch/lane
  float4 rd0, rd1, xd0, xd1;
  {
    uint4 rv = *(const uint4*)&xrh[(size_t)d * 256 + cb];
    cvt8(rv, rd0, rd1);
    uint4 xv = *(const uint4*)&xlh[(size_t)d * 256 + cb];
    cvt8(xv, xd0, xd1);
  }
  const float4 wa0 = *(const float4*)&att[cb];
  const float4 wa1 = *(const float4*)&att[cb + 4];
  const float4 s60 = make_float4(0.6f * wa0.x, 0.6f * wa0.y, 0.6f * wa0.z, 0.6f * wa0.w);
  const float4 s61 = make_float4(0.6f * wa1.x, 0.6f * wa1.y, 0.6f * wa1.z, 0.6f * wa1.w);
  const float4 s40 = make_float4(0.4f * wa0.x, 0.4f * wa0.y, 0.4f * wa0.z, 0.4f * wa0.w);
  const float4 s41 = make_float4(0.4f * wa1.x, 0.4f * wa1.y, 0.4f * wa1.z, 0.4f * wa1.w);
  float base;
  DOT8(xd0, xd1, base)
  RED(base)
  // chain A/B; self-loop seeded into half0 of chain A (w=1)
  float lA = half ? 0.f : 1.f, lB = 0.f;
  float4 aA0 = half ? make_float4(0.f, 0.f, 0.f, 0.f) : xd0;
  float4 aA1 = half ? make_float4(0.f, 0.f, 0.f, 0.f) : xd1;
  float4 aB0 = make_float4(0.f, 0.f, 0.f, 0.f);
  float4 aB1 = make_float4(0.f, 0.f, 0.f, 0.f);
  const int o0 = offs[d] + bsum[side * 256 + (d >> 8)];
  const int c = cnt[d];
  int j = 0;
  for (; j + 3 < c; j += 4) {
    int sA = csr[o0 + j + half];
    int sB = csr[o0 + j + 2 + half];
    uint4 vA = *(const uint4*)&xlh[(size_t)sA * 256 + cb];
    uint4 vB = *(const uint4*)&xlh[(size_t)sB * 256 + cb];
    float4 a0, a1, b0, b1;
    cvt8(vA, a0, a1);
    cvt8(vB, b0, b1);
    float qA, qB;
    DOT8(a0, a1, qA)
    DOT8(b0, b1, qB)
    RED(qA)
    RED(qB)
    float wA = __expf(qA - base), wB = __expf(qB - base);
    lA += wA; lB += wB;
    aA0.x = fmaf(wA, a0.x, aA0.x); aA0.y = fmaf(wA, a0.y, aA0.y);
    aA0.z = fmaf(wA, a0.z, aA0.z); aA0.w = fmaf(wA, a0.w, aA0.w);
    aA1.x = fmaf(wA, a1.x, aA1.x); aA1.y = fmaf(wA, a1.y, aA1.y);
    aA1.z = fmaf(wA, a1.z, aA1.z); aA1.w = fmaf(wA, a1.w, aA1.w);
    aB0.x = fmaf(wB, b0.x, aB0.x); aB0.y = fmaf(wB, b0.y, aB0.y);
    aB0.z = fmaf(wB, b0.z, aB0.z); aB0.w = fmaf(wB, b0.w, aB0.w);
    aB1.x = fmaf(wB, b1.x, aB1.x); aB1.y = fmaf(wB, b1.y, aB1.y);
    aB1.z = fmaf(wB, b1.z, aB1.z); aB1.w = fmaf(wB, b1.w, aB1.w);
  }
  for (; j < c; j += 2) {
    int e = j + half;
    bool valid = e < c;
    int sA = valid ? csr[o0 + e] : 0;
    uint4 vA = *(const uint4*)&xlh[(size_t)sA * 256 + cb];
    float4 a0, a1;
    cvt8(vA, a0, a1);
    float qA;
    DOT8(a0, a1, qA)
    RED(qA)
    float wA = valid ? __expf(qA - base) : 0.f;
    lA += wA;
    aA0.x = fmaf(wA, a0.x, aA0.x); aA0.y = fmaf(wA, a0.y, aA0.y);
    aA0.z = fmaf(wA, a0.z, aA0.z); aA0.w = fmaf(wA, a0.w, aA0.w);
    aA1.x = fmaf(wA, a1.x, aA1.x); aA1.y = fmaf(wA, a1.y, aA1.y);
    aA1.z = fmaf(wA, a1.z, aA1.z); aA1.w = fmaf(wA, a1.w, aA1.w);
  }
  // combine chains, then cross-half merge (lane i <-> i+32 hold identical channels)
  float l = lA + lB;
  float4 a0, a1;
  a0.x = aA0.x + aB0.x; a0.y = aA0.y + aB0.y; a0.z = aA0.z + aB0.z; a0.w = aA0.w + aB0.w;
  a1.x = aA1.x + aB1.x; a1.y = aA1.y + aB1.y; a1.z = aA1.z + aB1.z; a1.w = aA1.w + aB1.w;
  l += __shfl_xor(l, 32, 64);
  a0.x += __shfl_xor(a0.x, 32, 64);
  a0.y += __shfl_xor(a0.y, 32, 64);
  a0.z += __shfl_xor(a0.z, 32, 64);
  a0.w += __shfl_xor(a0.w, 32, 64);
  a1.x += __shfl_xor(a1.x, 32, 64);
  a1.y += __shfl_xor(a1.y, 32, 64);
  a1.z += __shfl_xor(a1.z, 32, 64);
  a1.w += __shfl_xor(a1.w, 32, 64);
  if (half == 0) {
    float inv = 1.f / l;
    const float4 b0 = *(const float4*)&bias[cb];
    const float4 b1 = *(const float4*)&bias[cb + 4];
    uint4 ov;
    ov.x = pk2bf(a0.x * inv + b0.x, a0.y * inv + b0.y);
    ov.y = pk2bf(a0.z * inv + b0.z, a0.w * inv + b0.w);
    ov.z = pk2bf(a1.x * inv + b1.x, a1.y * inv + b1.y);
    ov.w = pk2bf(a1.z * inv + b1.z, a1.w * inv + b1.w);
    *(uint4*)&out[(size_t)d * 256 + cb] = ov;
  }
}

// ---------------- chunked partial pool: grid (B, 2 sides, C chunks) ----------------
#define POOL_C 8
__global__ void k_pool_part(const u16* __restrict__ xp, const int* __restrict__ bp, int Np,
                            const u16* __restrict__ xl_, const int* __restrict__ bl_, int Nl,
                            float* __restrict__ PPpart, float* __restrict__ LPpart) {
  const int b = blockIdx.x;
  const int side = blockIdx.y;
  const int chunk = blockIdx.z;
  const u16* x = side ? xl_ : xp;
  const int* batch = side ? bl_ : bp;
  const int N = side ? Nl : Np;
  float* part = side ? LPpart : PPpart;
  int j = threadIdx.x;
  __shared__ int sss, sse;
  if (j == 0) {
    int lo = 0, hi = N;
    while (lo < hi) { int mid = (lo + hi) >> 1; if (batch[mid] < b) lo = mid + 1; else hi = mid; }
    sss = lo;
    lo = 0; hi = N;
    while (lo < hi) { int mid = (lo + hi) >> 1; if (batch[mid] < b + 1) lo = mid + 1; else hi = mid; }
    sse = lo;
  }
  __syncthreads();
  int len = sse - sss;
  int per = (len + POOL_C - 1) / POOL_C;
  int st = sss + chunk * per;
  int en = st + per;
  if (en > sse) en = sse;
  float acc = 0.f;
  for (int n = st; n < en; ++n) acc += bf2f(x[(size_t)n * 256 + j]);
  part[((size_t)chunk * 256 + b) * 256 + j] = acc;
}

// ---------------- head ----------------
__global__ void k_head(const float* __restrict__ PPpart, const float* __restrict__ LPpart,
                       const int* __restrict__ bp, int Np,
                       const int* __restrict__ bl_, int Nl,
                       const float* __restrict__ Wv, const float* __restrict__ bv,
                       const float* __restrict__ Wo, const float* __restrict__ bo,
                       const float* __restrict__ fc1w, const float* __restrict__ fc1b,
                       const float* __restrict__ lng, const float* __restrict__ lnb,
                       const float* __restrict__ fc2w, const float* __restrict__ fc2b,
                       float* __restrict__ out) {
  int b = blockIdx.x;
  int j = threadIdx.x;
  __shared__ float lxs[256];
  __shared__ float vbuf[256];
  __shared__ float comb[512];
  __shared__ float r1[256], r2[256];
  __shared__ float smu, srs;
  __shared__ int seg[4];
  if (j < 2) {
    const int* batch = j ? bl_ : bp;
    int N = j ? Nl : Np;
    int lo = 0, hi = N;
    while (lo < hi) { int mid = (lo + hi) >> 1; if (batch[mid] < b) lo = mid + 1; else hi = mid; }
    seg[j * 2] = lo;
    lo = 0; hi = N;
    while (lo < hi) { int mid = (lo + hi) >> 1; if (batch[mid] < b + 1) lo = mid + 1; else hi = mid; }
    seg[j * 2 + 1] = lo;
  }
  __syncthreads();
  {
    float accp = 0.f, accl = 0.f;
#pragma unroll
    for (int c = 0; c < POOL_C; ++c) {
      accp += PPpart[((size_t)c * 256 + b) * 256 + j];
      accl += LPpart[((size_t)c * 256 + b) * 256 + j];
    }
    comb[j] = accp / fmaxf((float)(seg[1] - seg[0]), 1.f);
    lxs[j] = accl / fmaxf((float)(seg[3] - seg[2]), 1.f);
  }
  __syncthreads();
  float v = bv[j];
  for (int k = 0; k < 256; ++k) v = fmaf(lxs[k], Wv[k * 256 + j], v);
  vbuf[j] = v;
  __syncthreads();
  float at = bo[j];
  for (int k = 0; k < 256; ++k) at = fmaf(vbuf[k], Wo[k * 256 + j], at);
  comb[256 + j] = at;
  __syncthreads();
  float h = fc1b[j];
  for (int k = 0; k < 512; ++k) h = fmaf(comb[k], fc1w[k * 256 + j], h);
  r1[j] = h;
  r2[j] = h * h;
  __syncthreads();
  for (int off = 128; off > 0; off >>= 1) {
    if (j < off) { r1[j] += r1[j + off]; r2[j] += r2[j + off]; }
    __syncthreads();
  }
  if (j == 0) {
    float mu = r1[0] / 256.f;
    float var = r2[0] / 256.f - mu * mu;
    smu = mu;
    srs = 1.f / sqrtf(var + 1e-5f);
  }
  __syncthreads();
  float hn = (h - smu) * srs * lng[j] + lnb[j];
  hn = hn > 0.f ? hn : 0.01f * hn;
  r1[j] = hn * fc2w[j];
  __syncthreads();
  for (int off = 128; off > 0; off >>= 1) {
    if (j < off) r1[j] += r1[j + off];
    __syncthreads();
  }
  if (j == 0) out[b] = r1[0] + fc2b[0];
}

extern "C" void kernel_launch(void* const* d_in, const int* in_sizes, int n_in,
                              void* d_out, int out_size, void* d_ws, size_t ws_size,
                              hipStream_t stream) {
  const float* px = (const float*)d_in[0];
  const float* lx = (const float*)d_in[1];
  const int* pei = (const int*)d_in[2];
  const int* lei = (const int*)d_in[3];
  const int* pb = (const int*)d_in[4];
  const int* lb = (const int*)d_in[5];
  const float* p1_Wl = (const float*)d_in[6];
  const float* p1_Wr = (const float*)d_in[7];
  const float* p1_att = (const float*)d_in[8];
  const float* p1_b = (const float*)d_in[9];
  const float* p2_Wl = (const float*)d_in[10];
  const float* p2_Wr = (const float*)d_in[11];
  const float* p2_att = (const float*)d_in[12];
  const float* p2_b = (const float*)d_in[13];
  const float* l1_Wl = (const float*)d_in[14];
  const float* l1_Wr = (const float*)d_in[15];
  const float* l1_att = (const float*)d_in[16];
  const float* l1_b = (const float*)d_in[17];
  const float* l2_Wl = (const float*)d_in[18];
  const float* l2_Wr = (const float*)d_in[19];
  const float* l2_att = (const float*)d_in[20];
  const float* l2_b = (const float*)d_in[21];
  const float* Wv = (const float*)d_in[26];
  const float* bv = (const float*)d_in[27];
  const float* Wo = (const float*)d_in[28];
  const float* bo = (const float*)d_in[29];
  const float* fc1w = (const float*)d_in[30];
  const float* fc1b = (const float*)d_in[31];
  const float* lng = (const float*)d_in[32];
  const float* lnb = (const float*)d_in[33];
  const float* fc2w = (const float*)d_in[34];
  const float* fc2b = (const float*)d_in[35];

  const int NPn = in_sizes[4];
  const int NLn = in_sizes[5];
  const int EPe = in_sizes[2] / 2;
  const int ELe = in_sizes[3] / 2;
  const int KP = in_sizes[0] / NPn;
  const int KL = in_sizes[1] / NLn;

  const int Nmax = NPn > NLn ? NPn : NLn;
  const int Emax = EPe > ELe ? EPe : ELe;
  size_t NF = (size_t)Nmax * 256;

  u16* XLh_p = (u16*)d_ws;
  u16* XRh_p = XLh_p + NF;
  u16* Ah_p = XRh_p + NF;
  u16* XLh_l = Ah_p + NF;
  u16* XRh_l = XLh_l + NF;
  u16* Ah_l = XRh_l + NF;
  u16* Wth = Ah_l + NF;  // 2 sides x 512*256
  u16* Wtl = Wth + 2 * 512 * 256;
  float* PPpart = (float*)(Wtl + 2 * 512 * 256);  // POOL_C x 256 x 256
  float* LPpart = PPpart + (size_t)POOL_C * 256 * 256;
  int* cnt = (int*)(LPpart + (size_t)POOL_C * 256 * 256);
  int* cur = cnt + 2 * (size_t)Nmax;
  int* offs = cur + 2 * (size_t)Nmax;
  int* bsum = offs + 2 * (size_t)Nmax;
  int* csr = bsum + 512;
  int* cnt_l = cnt + Nmax;
  int* cur_l = cur + Nmax;
  int* offs_l = offs + Nmax;
  int* csr_l = csr + Emax;

  const int nbp = (NPn + 255) / 256;
  const int nbl = (NLn + 255) / 256;
  const int nz = 2 * Nmax;
  const int zb = (nz + 255) / 256;
  const int linPer = (Nmax + 7) / 8;

  // setup: zero cnt + weight split + layer-1 linear (fused, independent block ranges)
  k_setup<<<zb + 1024 + 2 * linPer, 256, 0, stream>>>(
      cnt, nz, p2_Wl, p2_Wr, l2_Wl, l2_Wr,
      Wth, Wtl, Wth + 512 * 256, Wtl + 512 * 256,
      px, KP, NPn, lx, KL, NLn, p1_Wl, p1_Wr, l1_Wl, l1_Wr,
      XLh_p, XRh_p, XLh_l, XRh_l, linPer);
  // CSR build
  k_histb<<<(EPe + ELe + 255) / 256, 256, 0, stream>>>(pei, EPe, lei, ELe, cnt, cnt_l);
  k_scan1b<<<nbp + nbl, 256, 0, stream>>>(cnt, NPn, cnt_l, NLn, nbp, offs, offs_l,
                                          cur, cur_l, bsum);
  k_scan2b<<<2, 256, 0, stream>>>(bsum, nbp, nbl);
  k_fillb<<<(EPe + ELe + 255) / 256, 256, 0, stream>>>(pei, EPe, lei, ELe, offs, offs_l,
                                                       bsum, cur, cur_l, csr, csr_l);
  // layer 1 gather
  k_gat_gather_b<2><<<dim3((Nmax + 3) / 4, 2), 256, 0, stream>>>(
      XLh_p, XRh_p, Ah_p, XLh_l, XRh_l, Ah_l,
      csr, offs, cnt, csr_l, offs_l, cnt_l, bsum,
      p1_att, p1_b, l1_att, l1_b, NPn, NLn);
  // layer 2 GEMM (XCD-grouped swizzle)
  {
    const int Rp = (NPn + 127) / 128;
    const int Rl = (NLn + 127) / 128;
    const int Rtot = Rp + Rl;
    k_mm_dual_b<<<32 * ((Rtot + 7) / 8), 256, 0, stream>>>(
        Ah_p, Ah_l, Wth, Wtl, Wth + 512 * 256, Wtl + 512 * 256,
        XLh_p, XRh_p, XLh_l, XRh_l, NPn, NLn, Rp, Rtot);
  }
  k_gat_gather_b<1><<<dim3((Nmax + 3) / 4, 2), 256, 0, stream>>>(
      XLh_p, XRh_p, Ah_p, XLh_l, XRh_l, Ah_l,
      csr, offs, cnt, csr_l, offs_l, cnt_l, bsum,
      p2_att, p2_b, l2_att, l2_b, NPn, NLn);
  // pool (chunked partials) + head
  k_pool_part<<<dim3(256, 2, POOL_C), 256, 0, stream>>>(Ah_p, pb, NPn, Ah_l, lb, NLn,
                                                        PPpart, LPpart);
  k_head<<<256, 256, 0, stream>>>(PPpart, LPpart, pb, NPn, lb, NLn,
                                  Wv, bv, Wo, bo, fc1w, fc1b, lng, lnb, fc2w, fc2b,
                                  (float*)d_out);
  (void)n_in; (void)out_size; (void)ws_size;
}

// Round 14
// 569.293 us; speedup vs baseline: 1.0321x; 1.0321x over previous
//
#include <hip/hip_runtime.h>
#include <math.h>

typedef unsigned short u16;
typedef __attribute__((ext_vector_type(8))) short bf16x8;
typedef __attribute__((ext_vector_type(4))) float f32x4;

__device__ inline u16 f2bf(float x) {
  unsigned int u = __float_as_uint(x);
  u += 0x7fffu + ((u >> 16) & 1u);
  return (u16)(u >> 16);
}
__device__ inline float bf2f(u16 h) {
  return __uint_as_float(((unsigned int)h) << 16);
}
__device__ inline float4 ld_bf4(const u16* p) {
  ushort4 v = *(const ushort4*)p;
  return make_float4(bf2f(v.x), bf2f(v.y), bf2f(v.z), bf2f(v.w));
}

// ---------------- setup: zero cnt + weight split + layer-1 linear (fused) ----------------
__global__ void k_setup(int* __restrict__ cnt, int nz,
                        const float* __restrict__ W2pl, const float* __restrict__ W2pr,
                        const float* __restrict__ W2ll, const float* __restrict__ W2lr,
                        u16* __restrict__ Whp, u16* __restrict__ Wlp,
                        u16* __restrict__ Whl, u16* __restrict__ Wll_o,
                        const float* __restrict__ xp, int Kp, int Np,
                        const float* __restrict__ xl_, int Kl, int Nl,
                        const float* __restrict__ W1pl, const float* __restrict__ W1pr,
                        const float* __restrict__ W1ll, const float* __restrict__ W1lr,
                        u16* __restrict__ xlh_p, u16* __restrict__ xrh_p,
                        u16* __restrict__ xlh_l, u16* __restrict__ xrh_l,
                        int linPer) {
  const int zb = (nz + 255) / 256;
  if ((int)blockIdx.x < zb) {
    int i = blockIdx.x * 256 + threadIdx.x;
    if (i < nz) cnt[i] = 0;
    return;
  }
  int wb = blockIdx.x - zb;
  if (wb < 1024) {  // weight split
    int n = wb & 511;
    int side = wb >> 9;
    int col = n & 255;
    int k = threadIdx.x;
    const float* W = side == 0 ? (n < 256 ? W2pl : W2pr) : (n < 256 ? W2ll : W2lr);
    float w = W[k * 256 + col];
    u16* Wh = side ? Whl : Whp;
    u16* Wlo = side ? Wll_o : Wlp;
    u16 hb = f2bf(w);
    Wh[n * 256 + k] = hb;
    Wlo[n * 256 + k] = f2bf(w - bf2f(hb));
    return;
  }
  // layer-1 linear
  int wb2 = wb - 1024;
  const int side = wb2 / linPer;
  const float* x = side ? xl_ : xp;
  const int K = side ? Kl : Kp;
  const int N = side ? Nl : Np;
  const float* Wl = side ? W1ll : W1pl;
  const float* Wr = side ? W1lr : W1pr;
  u16* xlh = side ? xlh_l : xlh_p;
  u16* xrh = side ? xrh_l : xrh_p;
  int base = (wb2 - side * linPer) * 8;
  if (base >= N) return;
  int j = threadIdx.x;
  __shared__ float xs[8][16];
  int tot = 8 * K;
  for (int i = j; i < tot; i += 256) {
    int r = i / K, k = i - r * K;
    if (base + r < N) xs[r][k] = x[(size_t)(base + r) * K + k];
  }
  __syncthreads();
#pragma unroll
  for (int r = 0; r < 8; ++r) {
    int n = base + r;
    if (n >= N) break;
    float al = 0.f, ar = 0.f;
    for (int k = 0; k < K; ++k) {
      float xv = xs[r][k];
      al = fmaf(xv, Wl[k * 256 + j], al);
      ar = fmaf(xv, Wr[k * 256 + j], ar);
    }
    xlh[(size_t)n * 256 + j] = f2bf(al);
    xrh[(size_t)n * 256 + j] = f2bf(ar);
  }
}

// ---------------- histogram (both sides) ----------------
__global__ void k_histb(const int* __restrict__ eip, int Ep, const int* __restrict__ eil,
                        int El, int* __restrict__ cntp, int* __restrict__ cntl) {
  int e = blockIdx.x * blockDim.x + threadIdx.x;
  if (e < Ep) atomicAdd(&cntp[eip[Ep + e]], 1);
  else if (e < Ep + El) { int e2 = e - Ep; atomicAdd(&cntl[eil[El + e2]], 1); }
}

// ---------------- per-block scan (also zeroes cur) ----------------
__global__ void k_scan1b(const int* __restrict__ cntp, int Np, const int* __restrict__ cntl,
                         int Nl, int nbp, int* __restrict__ offsp, int* __restrict__ offsl,
                         int* __restrict__ curp, int* __restrict__ curl,
                         int* __restrict__ bsum) {
  __shared__ int s[256];
  int tid = threadIdx.x;
  int side = ((int)blockIdx.x >= nbp) ? 1 : 0;
  int blk = side ? (blockIdx.x - nbp) : blockIdx.x;
  const int* cnt = side ? cntl : cntp;
  int* offs = side ? offsl : offsp;
  int* cur = side ? curl : curp;
  int N = side ? Nl : Np;
  int i = blk * 256 + tid;
  int v = (i < N) ? cnt[i] : 0;
  if (i < N) cur[i] = 0;
  s[tid] = v;
  __syncthreads();
  for (int off = 1; off < 256; off <<= 1) {
    int t = 0;
    if (tid >= off) t = s[tid - off];
    __syncthreads();
    if (tid >= off) s[tid] += t;
    __syncthreads();
  }
  if (i < N) offs[i] = s[tid] - v;
  if (tid == 255) bsum[side * 256 + blk] = s[255];
}

__global__ void k_scan2b(int* __restrict__ bsum, int nbp, int nbl) {
  __shared__ int s[256];
  int side = blockIdx.x;
  int nb = side ? nbl : nbp;
  int* bs = bsum + side * 256;
  int tid = threadIdx.x;
  int v = (tid < nb) ? bs[tid] : 0;
  s[tid] = v;
  __syncthreads();
  for (int off = 1; off < 256; off <<= 1) {
    int t = 0;
    if (tid >= off) t = s[tid - off];
    __syncthreads();
    if (tid >= off) s[tid] += t;
    __syncthreads();
  }
  if (tid < nb) bs[tid] = s[tid] - v;
}

// ---------------- fill (bsum folded in) ----------------
__global__ void k_fillb(const int* __restrict__ eip, int Ep, const int* __restrict__ eil,
                        int El, const int* __restrict__ offsp, const int* __restrict__ offsl,
                        const int* __restrict__ bsum,
                        int* __restrict__ curp, int* __restrict__ curl,
                        int* __restrict__ csrp, int* __restrict__ csrl) {
  int e = blockIdx.x * blockDim.x + threadIdx.x;
  if (e < Ep) {
    int d = eip[Ep + e];
    int pos = offsp[d] + bsum[d >> 8] + atomicAdd(&curp[d], 1);
    csrp[pos] = eip[e];
  } else if (e < Ep + El) {
    int e2 = e - Ep;
    int d = eil[El + e2];
    int pos = offsl[d] + bsum[256 + (d >> 8)] + atomicAdd(&curl[d], 1);
    csrl[pos] = eil[e2];
  }
}

// ---------------- dual GEMM, 128x128 y=4 proven shape; XCD-grouped block swizzle ----------------
// NOTE: 128x256-wide tile regressed 2x with ~3.6x HBM write amplification (rounds 6, 11).
__global__ void __launch_bounds__(256, 2) k_mm_dual_b(
    const u16* __restrict__ A_p, const u16* __restrict__ A_l,
    const u16* __restrict__ Bh_p, const u16* __restrict__ Bl_p,
    const u16* __restrict__ Bh_l, const u16* __restrict__ Bl_l,
    u16* __restrict__ XLh_p, u16* __restrict__ XRh_p,
    u16* __restrict__ XLh_l, u16* __restrict__ XRh_l, int Np, int Nl, int Rp, int Rtot) {
  __shared__ __align__(16) char smem[32768];
  char* sA = smem;
  char* sBh = smem + 8192;
  char* sBl = smem + 16384;
  const int gid = blockIdx.x;
  const int rblk = (gid >> 5) * 8 + (gid & 7);
  const int col = (gid >> 3) & 3;
  if (rblk >= Rtot) return;
  const int side = (rblk >= Rp) ? 1 : 0;
  const int rloc = side ? rblk - Rp : rblk;
  const u16* A = side ? A_l : A_p;
  const u16* Bhi = side ? Bh_l : Bh_p;
  const u16* Blo = side ? Bl_l : Bl_p;
  u16* XLh = side ? XLh_l : XLh_p;
  u16* XRh = side ? XRh_l : XRh_p;
  const int M = side ? Nl : Np;
  const int t = threadIdx.x;
  const int rowBase = rloc * 128;
  const int j0 = col * 128;
  const int srow = t >> 1;
  const int h = t & 1;
  int gr = rowBase + srow;
  if (gr >= M) gr = M - 1;
  const size_t gaBase = (size_t)gr * 256 + h * 16;
  const size_t gbBase = (size_t)(j0 + srow) * 256 + h * 16;
  const int rb = srow * 64;
  const int sw0 = (((h * 2) + (srow >> 1)) & 3) * 16;
  const int sw1 = (((h * 2 + 1) + (srow >> 1)) & 3) * 16;
  const int lane = t & 63;
  const int wid = t >> 6;
  const int wm = (wid & 1) * 64;
  const int wn = (wid >> 1) * 64;
  const int kq = lane >> 4;
  const int mr = lane & 15;
  int offA[4], offB[4];
#pragma unroll
  for (int i = 0; i < 4; ++i) {
    int m = wm + i * 16 + mr;
    offA[i] = m * 64 + ((kq + (m >> 1)) & 3) * 16;
    int n = wn + i * 16 + mr;
    offB[i] = n * 64 + ((kq + (n >> 1)) & 3) * 16;
  }
  f32x4 acc[4][4] = {};
  for (int kt = 0; kt < 8; ++kt) {
    const int k0 = kt * 32;
    uint4 va0 = *(const uint4*)(A + gaBase + k0);
    uint4 va1 = *(const uint4*)(A + gaBase + k0 + 8);
    uint4 vbh0 = *(const uint4*)(Bhi + gbBase + k0);
    uint4 vbh1 = *(const uint4*)(Bhi + gbBase + k0 + 8);
    uint4 vbl0 = *(const uint4*)(Blo + gbBase + k0);
    uint4 vbl1 = *(const uint4*)(Blo + gbBase + k0 + 8);
    __syncthreads();
    *(uint4*)(sA + rb + sw0) = va0;
    *(uint4*)(sA + rb + sw1) = va1;
    *(uint4*)(sBh + rb + sw0) = vbh0;
    *(uint4*)(sBh + rb + sw1) = vbh1;
    *(uint4*)(sBl + rb + sw0) = vbl0;
    *(uint4*)(sBl + rb + sw1) = vbl1;
    __syncthreads();
    bf16x8 a[4], bh[4], bl[4];
#pragma unroll
    for (int i = 0; i < 4; ++i) {
      a[i] = *(const bf16x8*)(sA + offA[i]);
      bh[i] = *(const bf16x8*)(sBh + offB[i]);
      bl[i] = *(const bf16x8*)(sBl + offB[i]);
    }
#pragma unroll
    for (int i = 0; i < 4; ++i)
#pragma unroll
      for (int j = 0; j < 4; ++j) {
        acc[i][j] = __builtin_amdgcn_mfma_f32_16x16x32_bf16(a[i], bh[j], acc[i][j], 0, 0, 0);
        acc[i][j] = __builtin_amdgcn_mfma_f32_16x16x32_bf16(a[i], bl[j], acc[i][j], 0, 0, 0);
      }
  }
  __syncthreads();
  u16* wtile = (u16*)(smem + wid * 8192);
#pragma unroll
  for (int i = 0; i < 4; ++i)
#pragma unroll
    for (int j = 0; j < 4; ++j)
#pragma unroll
      for (int r = 0; r < 4; ++r)
        wtile[(i * 16 + kq * 4 + r) * 64 + j * 16 + mr] = f2bf(acc[i][j][r]);
  u16* cbase = (col < 2) ? XLh : XRh;
  const int cb = (col < 2) ? j0 : j0 - 256;
  const int r8 = lane >> 3;
  const int c8 = lane & 7;
#pragma unroll
  for (int rr = 0; rr < 8; ++rr) {
    int lr = rr * 8 + r8;
    uint4 v = *(const uint4*)&wtile[lr * 64 + c8 * 8];
    int row = rowBase + wm + lr;
    if (row < M) *(uint4*)&cbase[(size_t)row * 256 + cb + wn + c8 * 8] = v;
  }
}

// ---------------- GATv2 aggregation (round-12 proven: full wave, 4-acc, 4 loads in flight) ----------------
// lrelu(t)*wa == t*(0.6wa) + |t|*(0.4wa) exactly; softmax shift fixed at self logit.
// NOTE: half-wave (32 lanes x 8 ch) variant regressed (round 13): halves loads-in-flight,
// occupancy 61->45%. Keep full-wave 4-way unroll.
#define GAT_DOT(a, q)                                                          \
  {                                                                            \
    float t0 = a.x + rd.x, t1 = a.y + rd.y, t2 = a.z + rd.z, t3 = a.w + rd.w;  \
    q = fmaf(t3, wa6.w, fabsf(t3) * wa4.w);                                    \
    q = fmaf(fabsf(t2), wa4.z, fmaf(t2, wa6.z, q));                            \
    q = fmaf(fabsf(t1), wa4.y, fmaf(t1, wa6.y, q));                            \
    q = fmaf(fabsf(t0), wa4.x, fmaf(t0, wa6.x, q));                            \
  }

template <int H>
__global__ void k_gat_gather_b(
    const u16* __restrict__ xlh_p, const u16* __restrict__ xrh_p, u16* __restrict__ out_p,
    const u16* __restrict__ xlh_l, const u16* __restrict__ xrh_l, u16* __restrict__ out_l,
    const int* __restrict__ csr_p, const int* __restrict__ offs_p,
    const int* __restrict__ cnt_p,
    const int* __restrict__ csr_l, const int* __restrict__ offs_l,
    const int* __restrict__ cnt_l, const int* __restrict__ bsum,
    const float* __restrict__ att_p, const float* __restrict__ bias_p,
    const float* __restrict__ att_l, const float* __restrict__ bias_l,
    int Np, int Nl) {
  const int side = blockIdx.y;
  const u16* xlh = side ? xlh_l : xlh_p;
  const u16* xrh = side ? xrh_l : xrh_p;
  u16* out = side ? out_l : out_p;
  const int* csr = side ? csr_l : csr_p;
  const int* offs = side ? offs_l : offs_p;
  const int* cnt = side ? cnt_l : cnt_p;
  const float* att = side ? att_l : att_p;
  const float* bias = side ? bias_l : bias_p;
  const int N = side ? Nl : Np;
  int d = blockIdx.x * 4 + (threadIdx.x >> 6);
  if (d >= N) return;
  const int lo4 = (threadIdx.x & 63) * 4;
  const float4 rd = ld_bf4(&xrh[(size_t)d * 256 + lo4]);
  const float4 wa = *(const float4*)&att[lo4];
  const float4 wa6 = make_float4(0.6f * wa.x, 0.6f * wa.y, 0.6f * wa.z, 0.6f * wa.w);
  const float4 wa4 = make_float4(0.4f * wa.x, 0.4f * wa.y, 0.4f * wa.z, 0.4f * wa.w);
  const float4 xd = ld_bf4(&xlh[(size_t)d * 256 + lo4]);
  float base;
  GAT_DOT(xd, base)
#pragma unroll
  for (int off = 1; off <= (H == 2 ? 16 : 32); off <<= 1) base += __shfl_xor(base, off, 64);
  float l0 = 1.f, l1 = 0.f, l2 = 0.f, l3 = 0.f;
  float4 acc0 = xd;
  float4 acc1 = make_float4(0.f, 0.f, 0.f, 0.f);
  float4 acc2 = make_float4(0.f, 0.f, 0.f, 0.f);
  float4 acc3 = make_float4(0.f, 0.f, 0.f, 0.f);
  const int o0 = offs[d] + bsum[side * 256 + (d >> 8)];
  const int c = cnt[d];
  int j = 0;
  for (; j + 3 < c; j += 4) {
    int s0 = csr[o0 + j], s1 = csr[o0 + j + 1], s2 = csr[o0 + j + 2], s3 = csr[o0 + j + 3];
    float4 a0 = ld_bf4(&xlh[(size_t)s0 * 256 + lo4]);
    float4 a1 = ld_bf4(&xlh[(size_t)s1 * 256 + lo4]);
    float4 a2 = ld_bf4(&xlh[(size_t)s2 * 256 + lo4]);
    float4 a3 = ld_bf4(&xlh[(size_t)s3 * 256 + lo4]);
    float q0, q1, q2, q3;
    GAT_DOT(a0, q0)
    GAT_DOT(a1, q1)
    GAT_DOT(a2, q2)
    GAT_DOT(a3, q3)
#pragma unroll
    for (int off = 1; off <= (H == 2 ? 16 : 32); off <<= 1) {
      q0 += __shfl_xor(q0, off, 64);
      q1 += __shfl_xor(q1, off, 64);
      q2 += __shfl_xor(q2, off, 64);
      q3 += __shfl_xor(q3, off, 64);
    }
    float w0 = __expf(q0 - base), w1 = __expf(q1 - base);
    float w2 = __expf(q2 - base), w3 = __expf(q3 - base);
    l0 += w0; l1 += w1; l2 += w2; l3 += w3;
    acc0.x = fmaf(w0, a0.x, acc0.x); acc0.y = fmaf(w0, a0.y, acc0.y);
    acc0.z = fmaf(w0, a0.z, acc0.z); acc0.w = fmaf(w0, a0.w, acc0.w);
    acc1.x = fmaf(w1, a1.x, acc1.x); acc1.y = fmaf(w1, a1.y, acc1.y);
    acc1.z = fmaf(w1, a1.z, acc1.z); acc1.w = fmaf(w1, a1.w, acc1.w);
    acc2.x = fmaf(w2, a2.x, acc2.x); acc2.y = fmaf(w2, a2.y, acc2.y);
    acc2.z = fmaf(w2, a2.z, acc2.z); acc2.w = fmaf(w2, a2.w, acc2.w);
    acc3.x = fmaf(w3, a3.x, acc3.x); acc3.y = fmaf(w3, a3.y, acc3.y);
    acc3.z = fmaf(w3, a3.z, acc3.z); acc3.w = fmaf(w3, a3.w, acc3.w);
  }
  for (; j < c; ++j) {
    int s0 = csr[o0 + j];
    float4 a0 = ld_bf4(&xlh[(size_t)s0 * 256 + lo4]);
    float q0;
    GAT_DOT(a0, q0)
#pragma unroll
    for (int off = 1; off <= (H == 2 ? 16 : 32); off <<= 1) q0 += __shfl_xor(q0, off, 64);
    float w0 = __expf(q0 - base);
    l0 += w0;
    acc0.x = fmaf(w0, a0.x, acc0.x); acc0.y = fmaf(w0, a0.y, acc0.y);
    acc0.z = fmaf(w0, a0.z, acc0.z); acc0.w = fmaf(w0, a0.w, acc0.w);
  }
  float inv = 1.f / (l0 + l1 + l2 + l3);
  float ax = acc0.x + acc1.x + acc2.x + acc3.x;
  float ay = acc0.y + acc1.y + acc2.y + acc3.y;
  float az = acc0.z + acc1.z + acc2.z + acc3.z;
  float aw = acc0.w + acc1.w + acc2.w + acc3.w;
  const float4 b4 = *(const float4*)&bias[lo4];
  ushort4 hv;
  hv.x = f2bf(ax * inv + b4.x);
  hv.y = f2bf(ay * inv + b4.y);
  hv.z = f2bf(az * inv + b4.z);
  hv.w = f2bf(aw * inv + b4.w);
  *(ushort4*)&out[(size_t)d * 256 + lo4] = hv;
}

// ---------------- chunked partial pool: grid (B, 2 sides, C chunks) ----------------
#define POOL_C 8
__global__ void k_pool_part(const u16* __restrict__ xp, const int* __restrict__ bp, int Np,
                            const u16* __restrict__ xl_, const int* __restrict__ bl_, int Nl,
                            float* __restrict__ PPpart, float* __restrict__ LPpart) {
  const int b = blockIdx.x;
  const int side = blockIdx.y;
  const int chunk = blockIdx.z;
  const u16* x = side ? xl_ : xp;
  const int* batch = side ? bl_ : bp;
  const int N = side ? Nl : Np;
  float* part = side ? LPpart : PPpart;
  int j = threadIdx.x;
  __shared__ int sss, sse;
  if (j == 0) {
    int lo = 0, hi = N;
    while (lo < hi) { int mid = (lo + hi) >> 1; if (batch[mid] < b) lo = mid + 1; else hi = mid; }
    sss = lo;
    lo = 0; hi = N;
    while (lo < hi) { int mid = (lo + hi) >> 1; if (batch[mid] < b + 1) lo = mid + 1; else hi = mid; }
    sse = lo;
  }
  __syncthreads();
  int len = sse - sss;
  int per = (len + POOL_C - 1) / POOL_C;
  int st = sss + chunk * per;
  int en = st + per;
  if (en > sse) en = sse;
  float acc = 0.f;
  for (int n = st; n < en; ++n) acc += bf2f(x[(size_t)n * 256 + j]);
  part[((size_t)chunk * 256 + b) * 256 + j] = acc;
}

// ---------------- head ----------------
__global__ void k_head(const float* __restrict__ PPpart, const float* __restrict__ LPpart,
                       const int* __restrict__ bp, int Np,
                       const int* __restrict__ bl_, int Nl,
                       const float* __restrict__ Wv, const float* __restrict__ bv,
                       const float* __restrict__ Wo, const float* __restrict__ bo,
                       const float* __restrict__ fc1w, const float* __restrict__ fc1b,
                       const float* __restrict__ lng, const float* __restrict__ lnb,
                       const float* __restrict__ fc2w, const float* __restrict__ fc2b,
                       float* __restrict__ out) {
  int b = blockIdx.x;
  int j = threadIdx.x;
  __shared__ float lxs[256];
  __shared__ float vbuf[256];
  __shared__ float comb[512];
  __shared__ float r1[256], r2[256];
  __shared__ float smu, srs;
  __shared__ int seg[4];
  if (j < 2) {
    const int* batch = j ? bl_ : bp;
    int N = j ? Nl : Np;
    int lo = 0, hi = N;
    while (lo < hi) { int mid = (lo + hi) >> 1; if (batch[mid] < b) lo = mid + 1; else hi = mid; }
    seg[j * 2] = lo;
    lo = 0; hi = N;
    while (lo < hi) { int mid = (lo + hi) >> 1; if (batch[mid] < b + 1) lo = mid + 1; else hi = mid; }
    seg[j * 2 + 1] = lo;
  }
  __syncthreads();
  {
    float accp = 0.f, accl = 0.f;
#pragma unroll
    for (int c = 0; c < POOL_C; ++c) {
      accp += PPpart[((size_t)c * 256 + b) * 256 + j];
      accl += LPpart[((size_t)c * 256 + b) * 256 + j];
    }
    comb[j] = accp / fmaxf((float)(seg[1] - seg[0]), 1.f);
    lxs[j] = accl / fmaxf((float)(seg[3] - seg[2]), 1.f);
  }
  __syncthreads();
  float v = bv[j];
  for (int k = 0; k < 256; ++k) v = fmaf(lxs[k], Wv[k * 256 + j], v);
  vbuf[j] = v;
  __syncthreads();
  float at = bo[j];
  for (int k = 0; k < 256; ++k) at = fmaf(vbuf[k], Wo[k * 256 + j], at);
  comb[256 + j] = at;
  __syncthreads();
  float h = fc1b[j];
  for (int k = 0; k < 512; ++k) h = fmaf(comb[k], fc1w[k * 256 + j], h);
  r1[j] = h;
  r2[j] = h * h;
  __syncthreads();
  for (int off = 128; off > 0; off >>= 1) {
    if (j < off) { r1[j] += r1[j + off]; r2[j] += r2[j + off]; }
    __syncthreads();
  }
  if (j == 0) {
    float mu = r1[0] / 256.f;
    float var = r2[0] / 256.f - mu * mu;
    smu = mu;
    srs = 1.f / sqrtf(var + 1e-5f);
  }
  __syncthreads();
  float hn = (h - smu) * srs * lng[j] + lnb[j];
  hn = hn > 0.f ? hn : 0.01f * hn;
  r1[j] = hn * fc2w[j];
  __syncthreads();
  for (int off = 128; off > 0; off >>= 1) {
    if (j < off) r1[j] += r1[j + off];
    __syncthreads();
  }
  if (j == 0) out[b] = r1[0] + fc2b[0];
}

extern "C" void kernel_launch(void* const* d_in, const int* in_sizes, int n_in,
                              void* d_out, int out_size, void* d_ws, size_t ws_size,
                              hipStream_t stream) {
  const float* px = (const float*)d_in[0];
  const float* lx = (const float*)d_in[1];
  const int* pei = (const int*)d_in[2];
  const int* lei = (const int*)d_in[3];
  const int* pb = (const int*)d_in[4];
  const int* lb = (const int*)d_in[5];
  const float* p1_Wl = (const float*)d_in[6];
  const float* p1_Wr = (const float*)d_in[7];
  const float* p1_att = (const float*)d_in[8];
  const float* p1_b = (const float*)d_in[9];
  const float* p2_Wl = (const float*)d_in[10];
  const float* p2_Wr = (const float*)d_in[11];
  const float* p2_att = (const float*)d_in[12];
  const float* p2_b = (const float*)d_in[13];
  const float* l1_Wl = (const float*)d_in[14];
  const float* l1_Wr = (const float*)d_in[15];
  const float* l1_att = (const float*)d_in[16];
  const float* l1_b = (const float*)d_in[17];
  const float* l2_Wl = (const float*)d_in[18];
  const float* l2_Wr = (const float*)d_in[19];
  const float* l2_att = (const float*)d_in[20];
  const float* l2_b = (const float*)d_in[21];
  const float* Wv = (const float*)d_in[26];
  const float* bv = (const float*)d_in[27];
  const float* Wo = (const float*)d_in[28];
  const float* bo = (const float*)d_in[29];
  const float* fc1w = (const float*)d_in[30];
  const float* fc1b = (const float*)d_in[31];
  const float* lng = (const float*)d_in[32];
  const float* lnb = (const float*)d_in[33];
  const float* fc2w = (const float*)d_in[34];
  const float* fc2b = (const float*)d_in[35];

  const int NPn = in_sizes[4];
  const int NLn = in_sizes[5];
  const int EPe = in_sizes[2] / 2;
  const int ELe = in_sizes[3] / 2;
  const int KP = in_sizes[0] / NPn;
  const int KL = in_sizes[1] / NLn;

  const int Nmax = NPn > NLn ? NPn : NLn;
  const int Emax = EPe > ELe ? EPe : ELe;
  size_t NF = (size_t)Nmax * 256;

  u16* XLh_p = (u16*)d_ws;
  u16* XRh_p = XLh_p + NF;
  u16* Ah_p = XRh_p + NF;
  u16* XLh_l = Ah_p + NF;
  u16* XRh_l = XLh_l + NF;
  u16* Ah_l = XRh_l + NF;
  u16* Wth = Ah_l + NF;  // 2 sides x 512*256
  u16* Wtl = Wth + 2 * 512 * 256;
  float* PPpart = (float*)(Wtl + 2 * 512 * 256);  // POOL_C x 256 x 256
  float* LPpart = PPpart + (size_t)POOL_C * 256 * 256;
  int* cnt = (int*)(LPpart + (size_t)POOL_C * 256 * 256);
  int* cur = cnt + 2 * (size_t)Nmax;
  int* offs = cur + 2 * (size_t)Nmax;
  int* bsum = offs + 2 * (size_t)Nmax;
  int* csr = bsum + 512;
  int* cnt_l = cnt + Nmax;
  int* cur_l = cur + Nmax;
  int* offs_l = offs + Nmax;
  int* csr_l = csr + Emax;

  const int nbp = (NPn + 255) / 256;
  const int nbl = (NLn + 255) / 256;
  const int nz = 2 * Nmax;
  const int zb = (nz + 255) / 256;
  const int linPer = (Nmax + 7) / 8;

  // setup: zero cnt + weight split + layer-1 linear (fused)
  k_setup<<<zb + 1024 + 2 * linPer, 256, 0, stream>>>(
      cnt, nz, p2_Wl, p2_Wr, l2_Wl, l2_Wr,
      Wth, Wtl, Wth + 512 * 256, Wtl + 512 * 256,
      px, KP, NPn, lx, KL, NLn, p1_Wl, p1_Wr, l1_Wl, l1_Wr,
      XLh_p, XRh_p, XLh_l, XRh_l, linPer);
  // CSR build
  k_histb<<<(EPe + ELe + 255) / 256, 256, 0, stream>>>(pei, EPe, lei, ELe, cnt, cnt_l);
  k_scan1b<<<nbp + nbl, 256, 0, stream>>>(cnt, NPn, cnt_l, NLn, nbp, offs, offs_l,
                                          cur, cur_l, bsum);
  k_scan2b<<<2, 256, 0, stream>>>(bsum, nbp, nbl);
  k_fillb<<<(EPe + ELe + 255) / 256, 256, 0, stream>>>(pei, EPe, lei, ELe, offs, offs_l,
                                                       bsum, cur, cur_l, csr, csr_l);
  // layer 1 gather
  k_gat_gather_b<2><<<dim3((Nmax + 3) / 4, 2), 256, 0, stream>>>(
      XLh_p, XRh_p, Ah_p, XLh_l, XRh_l, Ah_l,
      csr, offs, cnt, csr_l, offs_l, cnt_l, bsum,
      p1_att, p1_b, l1_att, l1_b, NPn, NLn);
  // layer 2 GEMM (XCD-grouped swizzle)
  {
    const int Rp = (NPn + 127) / 128;
    const int Rl = (NLn + 127) / 128;
    const int Rtot = Rp + Rl;
    k_mm_dual_b<<<32 * ((Rtot + 7) / 8), 256, 0, stream>>>(
        Ah_p, Ah_l, Wth, Wtl, Wth + 512 * 256, Wtl + 512 * 256,
        XLh_p, XRh_p, XLh_l, XRh_l, NPn, NLn, Rp, Rtot);
  }
  k_gat_gather_b<1><<<dim3((Nmax + 3) / 4, 2), 256, 0, stream>>>(
      XLh_p, XRh_p, Ah_p, XLh_l, XRh_l, Ah_l,
      csr, offs, cnt, csr_l, offs_l, cnt_l, bsum,
      p2_att, p2_b, l2_att, l2_b, NPn, NLn);
  // pool (chunked partials) + head
  k_pool_part<<<dim3(256, 2, POOL_C), 256, 0, stream>>>(Ah_p, pb, NPn, Ah_l, lb, NLn,
                                                        PPpart, LPpart);
  k_head<<<256, 256, 0, stream>>>(PPpart, LPpart, pb, NPn, lb, NLn,
                                  Wv, bv, Wo, bo, fc1w, fc1b, lng, lnb, fc2w, fc2b,
                                  (float*)d_out);
  (void)n_in; (void)out_size; (void)ws_size;
}

// Round 15
// 548.190 us; speedup vs baseline: 1.0718x; 1.0385x over previous
//
#include <hip/hip_runtime.h>
#include <math.h>

typedef unsigned short u16;
typedef __attribute__((ext_vector_type(8))) short bf16x8;
typedef __attribute__((ext_vector_type(4))) float f32x4;

__device__ inline u16 f2bf(float x) {
  unsigned int u = __float_as_uint(x);
  u += 0x7fffu + ((u >> 16) & 1u);
  return (u16)(u >> 16);
}
__device__ inline float bf2f(u16 h) {
  return __uint_as_float(((unsigned int)h) << 16);
}
__device__ inline float4 ld_bf4(const u16* p) {
  ushort4 v = *(const ushort4*)p;
  return make_float4(bf2f(v.x), bf2f(v.y), bf2f(v.z), bf2f(v.w));
}

// ---------------- setup: zero cnt + weight split + layer-1 linear (fused) ----------------
__global__ void k_setup(int* __restrict__ cnt, int nz,
                        const float* __restrict__ W2pl, const float* __restrict__ W2pr,
                        const float* __restrict__ W2ll, const float* __restrict__ W2lr,
                        u16* __restrict__ Whp, u16* __restrict__ Wlp,
                        u16* __restrict__ Whl, u16* __restrict__ Wll_o,
                        const float* __restrict__ xp, int Kp, int Np,
                        const float* __restrict__ xl_, int Kl, int Nl,
                        const float* __restrict__ W1pl, const float* __restrict__ W1pr,
                        const float* __restrict__ W1ll, const float* __restrict__ W1lr,
                        u16* __restrict__ xlh_p, u16* __restrict__ xrh_p,
                        u16* __restrict__ xlh_l, u16* __restrict__ xrh_l,
                        int linPer) {
  const int zb = (nz + 255) / 256;
  if ((int)blockIdx.x < zb) {
    int i = blockIdx.x * 256 + threadIdx.x;
    if (i < nz) cnt[i] = 0;
    return;
  }
  int wb = blockIdx.x - zb;
  if (wb < 1024) {  // weight split
    int n = wb & 511;
    int side = wb >> 9;
    int col = n & 255;
    int k = threadIdx.x;
    const float* W = side == 0 ? (n < 256 ? W2pl : W2pr) : (n < 256 ? W2ll : W2lr);
    float w = W[k * 256 + col];
    u16* Wh = side ? Whl : Whp;
    u16* Wlo = side ? Wll_o : Wlp;
    u16 hb = f2bf(w);
    Wh[n * 256 + k] = hb;
    Wlo[n * 256 + k] = f2bf(w - bf2f(hb));
    return;
  }
  // layer-1 linear: k outer (W loaded once per k), 8-row accumulators inner
  int wb2 = wb - 1024;
  const int side = wb2 / linPer;
  const float* x = side ? xl_ : xp;
  const int K = side ? Kl : Kp;
  const int N = side ? Nl : Np;
  const float* Wl = side ? W1ll : W1pl;
  const float* Wr = side ? W1lr : W1pr;
  u16* xlh = side ? xlh_l : xlh_p;
  u16* xrh = side ? xrh_l : xrh_p;
  int base = (wb2 - side * linPer) * 8;
  if (base >= N) return;
  int j = threadIdx.x;
  __shared__ float xs[16][8];  // [k][r] transposed for broadcast reads
  int tot = 8 * K;
  for (int i = j; i < tot; i += 256) {
    int r = i / K, k = i - r * K;
    if (base + r < N) xs[k][r] = x[(size_t)(base + r) * K + k];
  }
  __syncthreads();
  float al[8] = {}, ar[8] = {};
  for (int k = 0; k < K; ++k) {
    float wl = Wl[k * 256 + j];
    float wr = Wr[k * 256 + j];
#pragma unroll
    for (int r = 0; r < 8; ++r) {
      al[r] = fmaf(xs[k][r], wl, al[r]);
      ar[r] = fmaf(xs[k][r], wr, ar[r]);
    }
  }
#pragma unroll
  for (int r = 0; r < 8; ++r) {
    int n = base + r;
    if (n < N) {
      xlh[(size_t)n * 256 + j] = f2bf(al[r]);
      xrh[(size_t)n * 256 + j] = f2bf(ar[r]);
    }
  }
}

// ---------------- histogram (both sides) ----------------
__global__ void k_histb(const int* __restrict__ eip, int Ep, const int* __restrict__ eil,
                        int El, int* __restrict__ cntp, int* __restrict__ cntl) {
  int e = blockIdx.x * blockDim.x + threadIdx.x;
  if (e < Ep) atomicAdd(&cntp[eip[Ep + e]], 1);
  else if (e < Ep + El) { int e2 = e - Ep; atomicAdd(&cntl[eil[El + e2]], 1); }
}

// ---------------- per-block scan (also zeroes cur) ----------------
__global__ void k_scan1b(const int* __restrict__ cntp, int Np, const int* __restrict__ cntl,
                         int Nl, int nbp, int* __restrict__ offsp, int* __restrict__ offsl,
                         int* __restrict__ curp, int* __restrict__ curl,
                         int* __restrict__ bsum) {
  __shared__ int s[256];
  int tid = threadIdx.x;
  int side = ((int)blockIdx.x >= nbp) ? 1 : 0;
  int blk = side ? (blockIdx.x - nbp) : blockIdx.x;
  const int* cnt = side ? cntl : cntp;
  int* offs = side ? offsl : offsp;
  int* cur = side ? curl : curp;
  int N = side ? Nl : Np;
  int i = blk * 256 + tid;
  int v = (i < N) ? cnt[i] : 0;
  if (i < N) cur[i] = 0;
  s[tid] = v;
  __syncthreads();
  for (int off = 1; off < 256; off <<= 1) {
    int t = 0;
    if (tid >= off) t = s[tid - off];
    __syncthreads();
    if (tid >= off) s[tid] += t;
    __syncthreads();
  }
  if (i < N) offs[i] = s[tid] - v;
  if (tid == 255) bsum[side * 256 + blk] = s[255];
}

__global__ void k_scan2b(int* __restrict__ bsum, int nbp, int nbl) {
  __shared__ int s[256];
  int side = blockIdx.x;
  int nb = side ? nbl : nbp;
  int* bs = bsum + side * 256;
  int tid = threadIdx.x;
  int v = (tid < nb) ? bs[tid] : 0;
  s[tid] = v;
  __syncthreads();
  for (int off = 1; off < 256; off <<= 1) {
    int t = 0;
    if (tid >= off) t = s[tid - off];
    __syncthreads();
    if (tid >= off) s[tid] += t;
    __syncthreads();
  }
  if (tid < nb) bs[tid] = s[tid] - v;
}

// ---------------- fill (bsum folded in) ----------------
__global__ void k_fillb(const int* __restrict__ eip, int Ep, const int* __restrict__ eil,
                        int El, const int* __restrict__ offsp, const int* __restrict__ offsl,
                        const int* __restrict__ bsum,
                        int* __restrict__ curp, int* __restrict__ curl,
                        int* __restrict__ csrp, int* __restrict__ csrl) {
  int e = blockIdx.x * blockDim.x + threadIdx.x;
  if (e < Ep) {
    int d = eip[Ep + e];
    int pos = offsp[d] + bsum[d >> 8] + atomicAdd(&curp[d], 1);
    csrp[pos] = eip[e];
  } else if (e < Ep + El) {
    int e2 = e - Ep;
    int d = eil[El + e2];
    int pos = offsl[d] + bsum[256 + (d >> 8)] + atomicAdd(&curl[d], 1);
    csrl[pos] = eil[e2];
  }
}

// ---------------- dual GEMM, 128x128 y=4 proven shape; XCD-grouped block swizzle ----------------
// NOTE: 128x256-wide tile regressed 2x with ~3.6x HBM write amplification (rounds 6, 11).
__global__ void __launch_bounds__(256, 2) k_mm_dual_b(
    const u16* __restrict__ A_p, const u16* __restrict__ A_l,
    const u16* __restrict__ Bh_p, const u16* __restrict__ Bl_p,
    const u16* __restrict__ Bh_l, const u16* __restrict__ Bl_l,
    u16* __restrict__ XLh_p, u16* __restrict__ XRh_p,
    u16* __restrict__ XLh_l, u16* __restrict__ XRh_l, int Np, int Nl, int Rp, int Rtot) {
  __shared__ __align__(16) char smem[32768];
  char* sA = smem;
  char* sBh = smem + 8192;
  char* sBl = smem + 16384;
  const int gid = blockIdx.x;
  const int rblk = (gid >> 5) * 8 + (gid & 7);
  const int col = (gid >> 3) & 3;
  if (rblk >= Rtot) return;
  const int side = (rblk >= Rp) ? 1 : 0;
  const int rloc = side ? rblk - Rp : rblk;
  const u16* A = side ? A_l : A_p;
  const u16* Bhi = side ? Bh_l : Bh_p;
  const u16* Blo = side ? Bl_l : Bl_p;
  u16* XLh = side ? XLh_l : XLh_p;
  u16* XRh = side ? XRh_l : XRh_p;
  const int M = side ? Nl : Np;
  const int t = threadIdx.x;
  const int rowBase = rloc * 128;
  const int j0 = col * 128;
  const int srow = t >> 1;
  const int h = t & 1;
  int gr = rowBase + srow;
  if (gr >= M) gr = M - 1;
  const size_t gaBase = (size_t)gr * 256 + h * 16;
  const size_t gbBase = (size_t)(j0 + srow) * 256 + h * 16;
  const int rb = srow * 64;
  const int sw0 = (((h * 2) + (srow >> 1)) & 3) * 16;
  const int sw1 = (((h * 2 + 1) + (srow >> 1)) & 3) * 16;
  const int lane = t & 63;
  const int wid = t >> 6;
  const int wm = (wid & 1) * 64;
  const int wn = (wid >> 1) * 64;
  const int kq = lane >> 4;
  const int mr = lane & 15;
  int offA[4], offB[4];
#pragma unroll
  for (int i = 0; i < 4; ++i) {
    int m = wm + i * 16 + mr;
    offA[i] = m * 64 + ((kq + (m >> 1)) & 3) * 16;
    int n = wn + i * 16 + mr;
    offB[i] = n * 64 + ((kq + (n >> 1)) & 3) * 16;
  }
  f32x4 acc[4][4] = {};
  for (int kt = 0; kt < 8; ++kt) {
    const int k0 = kt * 32;
    uint4 va0 = *(const uint4*)(A + gaBase + k0);
    uint4 va1 = *(const uint4*)(A + gaBase + k0 + 8);
    uint4 vbh0 = *(const uint4*)(Bhi + gbBase + k0);
    uint4 vbh1 = *(const uint4*)(Bhi + gbBase + k0 + 8);
    uint4 vbl0 = *(const uint4*)(Blo + gbBase + k0);
    uint4 vbl1 = *(const uint4*)(Blo + gbBase + k0 + 8);
    __syncthreads();
    *(uint4*)(sA + rb + sw0) = va0;
    *(uint4*)(sA + rb + sw1) = va1;
    *(uint4*)(sBh + rb + sw0) = vbh0;
    *(uint4*)(sBh + rb + sw1) = vbh1;
    *(uint4*)(sBl + rb + sw0) = vbl0;
    *(uint4*)(sBl + rb + sw1) = vbl1;
    __syncthreads();
    bf16x8 a[4], bh[4], bl[4];
#pragma unroll
    for (int i = 0; i < 4; ++i) {
      a[i] = *(const bf16x8*)(sA + offA[i]);
      bh[i] = *(const bf16x8*)(sBh + offB[i]);
      bl[i] = *(const bf16x8*)(sBl + offB[i]);
    }
#pragma unroll
    for (int i = 0; i < 4; ++i)
#pragma unroll
      for (int j = 0; j < 4; ++j) {
        acc[i][j] = __builtin_amdgcn_mfma_f32_16x16x32_bf16(a[i], bh[j], acc[i][j], 0, 0, 0);
        acc[i][j] = __builtin_amdgcn_mfma_f32_16x16x32_bf16(a[i], bl[j], acc[i][j], 0, 0, 0);
      }
  }
  __syncthreads();
  u16* wtile = (u16*)(smem + wid * 8192);
#pragma unroll
  for (int i = 0; i < 4; ++i)
#pragma unroll
    for (int j = 0; j < 4; ++j)
#pragma unroll
      for (int r = 0; r < 4; ++r)
        wtile[(i * 16 + kq * 4 + r) * 64 + j * 16 + mr] = f2bf(acc[i][j][r]);
  u16* cbase = (col < 2) ? XLh : XRh;
  const int cb = (col < 2) ? j0 : j0 - 256;
  const int r8 = lane >> 3;
  const int c8 = lane & 7;
#pragma unroll
  for (int rr = 0; rr < 8; ++rr) {
    int lr = rr * 8 + r8;
    uint4 v = *(const uint4*)&wtile[lr * 64 + c8 * 8];
    int row = rowBase + wm + lr;
    if (row < M) *(uint4*)&cbase[(size_t)row * 256 + cb + wn + c8 * 8] = v;
  }
}

// ---------------- GATv2 aggregation (full wave, 4-acc, csr index prefetch) ----------------
// lrelu(t)*wa == t*(0.6wa) + |t|*(0.4wa) exactly; softmax shift fixed at self logit.
// NOTE: half-wave (32 lanes x 8 ch) variant regressed (round 13): halves loads-in-flight.
#define GAT_DOT(a, q)                                                          \
  {                                                                            \
    float t0 = a.x + rd.x, t1 = a.y + rd.y, t2 = a.z + rd.z, t3 = a.w + rd.w;  \
    q = fmaf(t3, wa6.w, fabsf(t3) * wa4.w);                                    \
    q = fmaf(fabsf(t2), wa4.z, fmaf(t2, wa6.z, q));                            \
    q = fmaf(fabsf(t1), wa4.y, fmaf(t1, wa6.y, q));                            \
    q = fmaf(fabsf(t0), wa4.x, fmaf(t0, wa6.x, q));                            \
  }

template <int H>
__global__ void k_gat_gather_b(
    const u16* __restrict__ xlh_p, const u16* __restrict__ xrh_p, u16* __restrict__ out_p,
    const u16* __restrict__ xlh_l, const u16* __restrict__ xrh_l, u16* __restrict__ out_l,
    const int* __restrict__ csr_p, const int* __restrict__ offs_p,
    const int* __restrict__ cnt_p,
    const int* __restrict__ csr_l, const int* __restrict__ offs_l,
    const int* __restrict__ cnt_l, const int* __restrict__ bsum,
    const float* __restrict__ att_p, const float* __restrict__ bias_p,
    const float* __restrict__ att_l, const float* __restrict__ bias_l,
    int Np, int Nl) {
  const int side = blockIdx.y;
  const u16* xlh = side ? xlh_l : xlh_p;
  const u16* xrh = side ? xrh_l : xrh_p;
  u16* out = side ? out_l : out_p;
  const int* csr = side ? csr_l : csr_p;
  const int* offs = side ? offs_l : offs_p;
  const int* cnt = side ? cnt_l : cnt_p;
  const float* att = side ? att_l : att_p;
  const float* bias = side ? bias_l : bias_p;
  const int N = side ? Nl : Np;
  int d = blockIdx.x * 4 + (threadIdx.x >> 6);
  if (d >= N) return;
  const int lo4 = (threadIdx.x & 63) * 4;
  const float4 rd = ld_bf4(&xrh[(size_t)d * 256 + lo4]);
  const float4 wa = *(const float4*)&att[lo4];
  const float4 wa6 = make_float4(0.6f * wa.x, 0.6f * wa.y, 0.6f * wa.z, 0.6f * wa.w);
  const float4 wa4 = make_float4(0.4f * wa.x, 0.4f * wa.y, 0.4f * wa.z, 0.4f * wa.w);
  const float4 xd = ld_bf4(&xlh[(size_t)d * 256 + lo4]);
  float base;
  GAT_DOT(xd, base)
#pragma unroll
  for (int off = 1; off <= (H == 2 ? 16 : 32); off <<= 1) base += __shfl_xor(base, off, 64);
  float l0 = 1.f, l1 = 0.f, l2 = 0.f, l3 = 0.f;
  float4 acc0 = xd;
  float4 acc1 = make_float4(0.f, 0.f, 0.f, 0.f);
  float4 acc2 = make_float4(0.f, 0.f, 0.f, 0.f);
  float4 acc3 = make_float4(0.f, 0.f, 0.f, 0.f);
  const int o0 = offs[d] + bsum[side * 256 + (d >> 8)];
  const int c = cnt[d];
  int j = 0;
  int s0 = 0, s1 = 0, s2 = 0, s3 = 0;
  if (c > 3) {
    s0 = csr[o0];
    s1 = csr[o0 + 1];
    s2 = csr[o0 + 2];
    s3 = csr[o0 + 3];
  }
  for (; j + 3 < c; j += 4) {
    float4 a0 = ld_bf4(&xlh[(size_t)s0 * 256 + lo4]);
    float4 a1 = ld_bf4(&xlh[(size_t)s1 * 256 + lo4]);
    float4 a2 = ld_bf4(&xlh[(size_t)s2 * 256 + lo4]);
    float4 a3 = ld_bf4(&xlh[(size_t)s3 * 256 + lo4]);
    // prefetch next iteration's indices (clamped in-bounds; unused past loop end)
    int cm = c - 1;
    s0 = csr[o0 + (j + 4 < cm ? j + 4 : cm)];
    s1 = csr[o0 + (j + 5 < cm ? j + 5 : cm)];
    s2 = csr[o0 + (j + 6 < cm ? j + 6 : cm)];
    s3 = csr[o0 + (j + 7 < cm ? j + 7 : cm)];
    float q0, q1, q2, q3;
    GAT_DOT(a0, q0)
    GAT_DOT(a1, q1)
    GAT_DOT(a2, q2)
    GAT_DOT(a3, q3)
#pragma unroll
    for (int off = 1; off <= (H == 2 ? 16 : 32); off <<= 1) {
      q0 += __shfl_xor(q0, off, 64);
      q1 += __shfl_xor(q1, off, 64);
      q2 += __shfl_xor(q2, off, 64);
      q3 += __shfl_xor(q3, off, 64);
    }
    float w0 = __expf(q0 - base), w1 = __expf(q1 - base);
    float w2 = __expf(q2 - base), w3 = __expf(q3 - base);
    l0 += w0; l1 += w1; l2 += w2; l3 += w3;
    acc0.x = fmaf(w0, a0.x, acc0.x); acc0.y = fmaf(w0, a0.y, acc0.y);
    acc0.z = fmaf(w0, a0.z, acc0.z); acc0.w = fmaf(w0, a0.w, acc0.w);
    acc1.x = fmaf(w1, a1.x, acc1.x); acc1.y = fmaf(w1, a1.y, acc1.y);
    acc1.z = fmaf(w1, a1.z, acc1.z); acc1.w = fmaf(w1, a1.w, acc1.w);
    acc2.x = fmaf(w2, a2.x, acc2.x); acc2.y = fmaf(w2, a2.y, acc2.y);
    acc2.z = fmaf(w2, a2.z, acc2.z); acc2.w = fmaf(w2, a2.w, acc2.w);
    acc3.x = fmaf(w3, a3.x, acc3.x); acc3.y = fmaf(w3, a3.y, acc3.y);
    acc3.z = fmaf(w3, a3.z, acc3.z); acc3.w = fmaf(w3, a3.w, acc3.w);
  }
  for (; j < c; ++j) {
    int sx = csr[o0 + j];
    float4 a0 = ld_bf4(&xlh[(size_t)sx * 256 + lo4]);
    float q0;
    GAT_DOT(a0, q0)
#pragma unroll
    for (int off = 1; off <= (H == 2 ? 16 : 32); off <<= 1) q0 += __shfl_xor(q0, off, 64);
    float w0 = __expf(q0 - base);
    l0 += w0;
    acc0.x = fmaf(w0, a0.x, acc0.x); acc0.y = fmaf(w0, a0.y, acc0.y);
    acc0.z = fmaf(w0, a0.z, acc0.z); acc0.w = fmaf(w0, a0.w, acc0.w);
  }
  float inv = 1.f / (l0 + l1 + l2 + l3);
  float ax = acc0.x + acc1.x + acc2.x + acc3.x;
  float ay = acc0.y + acc1.y + acc2.y + acc3.y;
  float az = acc0.z + acc1.z + acc2.z + acc3.z;
  float aw = acc0.w + acc1.w + acc2.w + acc3.w;
  const float4 b4 = *(const float4*)&bias[lo4];
  ushort4 hv;
  hv.x = f2bf(ax * inv + b4.x);
  hv.y = f2bf(ay * inv + b4.y);
  hv.z = f2bf(az * inv + b4.z);
  hv.w = f2bf(aw * inv + b4.w);
  *(ushort4*)&out[(size_t)d * 256 + lo4] = hv;
}

// ---------------- chunked partial pool: grid (B, 2 sides, C chunks) ----------------
#define POOL_C 8
__global__ void k_pool_part(const u16* __restrict__ xp, const int* __restrict__ bp, int Np,
                            const u16* __restrict__ xl_, const int* __restrict__ bl_, int Nl,
                            float* __restrict__ PPpart, float* __restrict__ LPpart) {
  const int b = blockIdx.x;
  const int side = blockIdx.y;
  const int chunk = blockIdx.z;
  const u16* x = side ? xl_ : xp;
  const int* batch = side ? bl_ : bp;
  const int N = side ? Nl : Np;
  float* part = side ? LPpart : PPpart;
  int j = threadIdx.x;
  __shared__ int sss, sse;
  if (j == 0) {
    int lo = 0, hi = N;
    while (lo < hi) { int mid = (lo + hi) >> 1; if (batch[mid] < b) lo = mid + 1; else hi = mid; }
    sss = lo;
    lo = 0; hi = N;
    while (lo < hi) { int mid = (lo + hi) >> 1; if (batch[mid] < b + 1) lo = mid + 1; else hi = mid; }
    sse = lo;
  }
  __syncthreads();
  int len = sse - sss;
  int per = (len + POOL_C - 1) / POOL_C;
  int st = sss + chunk * per;
  int en = st + per;
  if (en > sse) en = sse;
  float acc = 0.f;
  for (int n = st; n < en; ++n) acc += bf2f(x[(size_t)n * 256 + j]);
  part[((size_t)chunk * 256 + b) * 256 + j] = acc;
}

// ---------------- head ----------------
__global__ void k_head(const float* __restrict__ PPpart, const float* __restrict__ LPpart,
                       const int* __restrict__ bp, int Np,
                       const int* __restrict__ bl_, int Nl,
                       const float* __restrict__ Wv, const float* __restrict__ bv,
                       const float* __restrict__ Wo, const float* __restrict__ bo,
                       const float* __restrict__ fc1w, const float* __restrict__ fc1b,
                       const float* __restrict__ lng, const float* __restrict__ lnb,
                       const float* __restrict__ fc2w, const float* __restrict__ fc2b,
                       float* __restrict__ out) {
  int b = blockIdx.x;
  int j = threadIdx.x;
  __shared__ float lxs[256];
  __shared__ float vbuf[256];
  __shared__ float comb[512];
  __shared__ float r1[256], r2[256];
  __shared__ float smu, srs;
  __shared__ int seg[4];
  if (j < 2) {
    const int* batch = j ? bl_ : bp;
    int N = j ? Nl : Np;
    int lo = 0, hi = N;
    while (lo < hi) { int mid = (lo + hi) >> 1; if (batch[mid] < b) lo = mid + 1; else hi = mid; }
    seg[j * 2] = lo;
    lo = 0; hi = N;
    while (lo < hi) { int mid = (lo + hi) >> 1; if (batch[mid] < b + 1) lo = mid + 1; else hi = mid; }
    seg[j * 2 + 1] = lo;
  }
  __syncthreads();
  {
    float accp = 0.f, accl = 0.f;
#pragma unroll
    for (int c = 0; c < POOL_C; ++c) {
      accp += PPpart[((size_t)c * 256 + b) * 256 + j];
      accl += LPpart[((size_t)c * 256 + b) * 256 + j];
    }
    comb[j] = accp / fmaxf((float)(seg[1] - seg[0]), 1.f);
    lxs[j] = accl / fmaxf((float)(seg[3] - seg[2]), 1.f);
  }
  __syncthreads();
  float v = bv[j];
  for (int k = 0; k < 256; ++k) v = fmaf(lxs[k], Wv[k * 256 + j], v);
  vbuf[j] = v;
  __syncthreads();
  float at = bo[j];
  for (int k = 0; k < 256; ++k) at = fmaf(vbuf[k], Wo[k * 256 + j], at);
  comb[256 + j] = at;
  __syncthreads();
  float h = fc1b[j];
  for (int k = 0; k < 512; ++k) h = fmaf(comb[k], fc1w[k * 256 + j], h);
  r1[j] = h;
  r2[j] = h * h;
  __syncthreads();
  for (int off = 128; off > 0; off >>= 1) {
    if (j < off) { r1[j] += r1[j + off]; r2[j] += r2[j + off]; }
    __syncthreads();
  }
  if (j == 0) {
    float mu = r1[0] / 256.f;
    float var = r2[0] / 256.f - mu * mu;
    smu = mu;
    srs = 1.f / sqrtf(var + 1e-5f);
  }
  __syncthreads();
  float hn = (h - smu) * srs * lng[j] + lnb[j];
  hn = hn > 0.f ? hn : 0.01f * hn;
  r1[j] = hn * fc2w[j];
  __syncthreads();
  for (int off = 128; off > 0; off >>= 1) {
    if (j < off) r1[j] += r1[j + off];
    __syncthreads();
  }
  if (j == 0) out[b] = r1[0] + fc2b[0];
}

extern "C" void kernel_launch(void* const* d_in, const int* in_sizes, int n_in,
                              void* d_out, int out_size, void* d_ws, size_t ws_size,
                              hipStream_t stream) {
  const float* px = (const float*)d_in[0];
  const float* lx = (const float*)d_in[1];
  const int* pei = (const int*)d_in[2];
  const int* lei = (const int*)d_in[3];
  const int* pb = (const int*)d_in[4];
  const int* lb = (const int*)d_in[5];
  const float* p1_Wl = (const float*)d_in[6];
  const float* p1_Wr = (const float*)d_in[7];
  const float* p1_att = (const float*)d_in[8];
  const float* p1_b = (const float*)d_in[9];
  const float* p2_Wl = (const float*)d_in[10];
  const float* p2_Wr = (const float*)d_in[11];
  const float* p2_att = (const float*)d_in[12];
  const float* p2_b = (const float*)d_in[13];
  const float* l1_Wl = (const float*)d_in[14];
  const float* l1_Wr = (const float*)d_in[15];
  const float* l1_att = (const float*)d_in[16];
  const float* l1_b = (const float*)d_in[17];
  const float* l2_Wl = (const float*)d_in[18];
  const float* l2_Wr = (const float*)d_in[19];
  const float* l2_att = (const float*)d_in[20];
  const float* l2_b = (const float*)d_in[21];
  const float* Wv = (const float*)d_in[26];
  const float* bv = (const float*)d_in[27];
  const float* Wo = (const float*)d_in[28];
  const float* bo = (const float*)d_in[29];
  const float* fc1w = (const float*)d_in[30];
  const float* fc1b = (const float*)d_in[31];
  const float* lng = (const float*)d_in[32];
  const float* lnb = (const float*)d_in[33];
  const float* fc2w = (const float*)d_in[34];
  const float* fc2b = (const float*)d_in[35];

  const int NPn = in_sizes[4];
  const int NLn = in_sizes[5];
  const int EPe = in_sizes[2] / 2;
  const int ELe = in_sizes[3] / 2;
  const int KP = in_sizes[0] / NPn;
  const int KL = in_sizes[1] / NLn;

  const int Nmax = NPn > NLn ? NPn : NLn;
  const int Emax = EPe > ELe ? EPe : ELe;
  size_t NF = (size_t)Nmax * 256;

  u16* XLh_p = (u16*)d_ws;
  u16* XRh_p = XLh_p + NF;
  u16* Ah_p = XRh_p + NF;
  u16* XLh_l = Ah_p + NF;
  u16* XRh_l = XLh_l + NF;
  u16* Ah_l = XRh_l + NF;
  u16* Wth = Ah_l + NF;  // 2 sides x 512*256
  u16* Wtl = Wth + 2 * 512 * 256;
  float* PPpart = (float*)(Wtl + 2 * 512 * 256);  // POOL_C x 256 x 256
  float* LPpart = PPpart + (size_t)POOL_C * 256 * 256;
  int* cnt = (int*)(LPpart + (size_t)POOL_C * 256 * 256);
  int* cur = cnt + 2 * (size_t)Nmax;
  int* offs = cur + 2 * (size_t)Nmax;
  int* bsum = offs + 2 * (size_t)Nmax;
  int* csr = bsum + 512;
  int* cnt_l = cnt + Nmax;
  int* cur_l = cur + Nmax;
  int* offs_l = offs + Nmax;
  int* csr_l = csr + Emax;

  const int nbp = (NPn + 255) / 256;
  const int nbl = (NLn + 255) / 256;
  const int nz = 2 * Nmax;
  const int zb = (nz + 255) / 256;
  const int linPer = (Nmax + 7) / 8;

  // setup: zero cnt + weight split + layer-1 linear (fused)
  k_setup<<<zb + 1024 + 2 * linPer, 256, 0, stream>>>(
      cnt, nz, p2_Wl, p2_Wr, l2_Wl, l2_Wr,
      Wth, Wtl, Wth + 512 * 256, Wtl + 512 * 256,
      px, KP, NPn, lx, KL, NLn, p1_Wl, p1_Wr, l1_Wl, l1_Wr,
      XLh_p, XRh_p, XLh_l, XRh_l, linPer);
  // CSR build
  k_histb<<<(EPe + ELe + 255) / 256, 256, 0, stream>>>(pei, EPe, lei, ELe, cnt, cnt_l);
  k_scan1b<<<nbp + nbl, 256, 0, stream>>>(cnt, NPn, cnt_l, NLn, nbp, offs, offs_l,
                                          cur, cur_l, bsum);
  k_scan2b<<<2, 256, 0, stream>>>(bsum, nbp, nbl);
  k_fillb<<<(EPe + ELe + 255) / 256, 256, 0, stream>>>(pei, EPe, lei, ELe, offs, offs_l,
                                                       bsum, cur, cur_l, csr, csr_l);
  // layer 1 gather
  k_gat_gather_b<2><<<dim3((Nmax + 3) / 4, 2), 256, 0, stream>>>(
      XLh_p, XRh_p, Ah_p, XLh_l, XRh_l, Ah_l,
      csr, offs, cnt, csr_l, offs_l, cnt_l, bsum,
      p1_att, p1_b, l1_att, l1_b, NPn, NLn);
  // layer 2 GEMM (XCD-grouped swizzle)
  {
    const int Rp = (NPn + 127) / 128;
    const int Rl = (NLn + 127) / 128;
    const int Rtot = Rp + Rl;
    k_mm_dual_b<<<32 * ((Rtot + 7) / 8), 256, 0, stream>>>(
        Ah_p, Ah_l, Wth, Wtl, Wth + 512 * 256, Wtl + 512 * 256,
        XLh_p, XRh_p, XLh_l, XRh_l, NPn, NLn, Rp, Rtot);
  }
  k_gat_gather_b<1><<<dim3((Nmax + 3) / 4, 2), 256, 0, stream>>>(
      XLh_p, XRh_p, Ah_p, XLh_l, XRh_l, Ah_l,
      csr, offs, cnt, csr_l, offs_l, cnt_l, bsum,
      p2_att, p2_b, l2_att, l2_b, NPn, NLn);
  // pool (chunked partials) + head
  k_pool_part<<<dim3(256, 2, POOL_C), 256, 0, stream>>>(Ah_p, pb, NPn, Ah_l, lb, NLn,
                                                        PPpart, LPpart);
  k_head<<<256, 256, 0, stream>>>(PPpart, LPpart, pb, NPn, lb, NLn,
                                  Wv, bv, Wo, bo, fc1w, fc1b, lng, lnb, fc2w, fc2b,
                                  (float*)d_out);
  (void)n_in; (void)out_size; (void)ws_size;
}

// Round 16
// 529.308 us; speedup vs baseline: 1.1101x; 1.0357x over previous
//
#include <hip/hip_runtime.h>
#include <math.h>

typedef unsigned short u16;
typedef __attribute__((ext_vector_type(8))) short bf16x8;
typedef __attribute__((ext_vector_type(4))) float f32x4;

__device__ inline u16 f2bf(float x) {
  unsigned int u = __float_as_uint(x);
  u += 0x7fffu + ((u >> 16) & 1u);
  return (u16)(u >> 16);
}
__device__ inline float bf2f(u16 h) {
  return __uint_as_float(((unsigned int)h) << 16);
}
__device__ inline float4 ld_bf4(const u16* p) {
  ushort4 v = *(const ushort4*)p;
  return make_float4(bf2f(v.x), bf2f(v.y), bf2f(v.z), bf2f(v.w));
}

// ---------------- setup: zero cnt + weight split + layer-1 linear (fused) ----------------
// lin loop interchanged (k outer): 20 W-loads + 160 FMAs per thread (round-15 win, ~55 us).
__global__ void k_setup(int* __restrict__ cnt, int nz,
                        const float* __restrict__ W2pl, const float* __restrict__ W2pr,
                        const float* __restrict__ W2ll, const float* __restrict__ W2lr,
                        u16* __restrict__ Whp, u16* __restrict__ Wlp,
                        u16* __restrict__ Whl, u16* __restrict__ Wll_o,
                        const float* __restrict__ xp, int Kp, int Np,
                        const float* __restrict__ xl_, int Kl, int Nl,
                        const float* __restrict__ W1pl, const float* __restrict__ W1pr,
                        const float* __restrict__ W1ll, const float* __restrict__ W1lr,
                        u16* __restrict__ xlh_p, u16* __restrict__ xrh_p,
                        u16* __restrict__ xlh_l, u16* __restrict__ xrh_l,
                        int linPer) {
  const int zb = (nz + 255) / 256;
  if ((int)blockIdx.x < zb) {
    int i = blockIdx.x * 256 + threadIdx.x;
    if (i < nz) cnt[i] = 0;
    return;
  }
  int wb = blockIdx.x - zb;
  if (wb < 1024) {  // weight split
    int n = wb & 511;
    int side = wb >> 9;
    int col = n & 255;
    int k = threadIdx.x;
    const float* W = side == 0 ? (n < 256 ? W2pl : W2pr) : (n < 256 ? W2ll : W2lr);
    float w = W[k * 256 + col];
    u16* Wh = side ? Whl : Whp;
    u16* Wlo = side ? Wll_o : Wlp;
    u16 hb = f2bf(w);
    Wh[n * 256 + k] = hb;
    Wlo[n * 256 + k] = f2bf(w - bf2f(hb));
    return;
  }
  // layer-1 linear: k outer (W loaded once per k), 8-row accumulators inner
  int wb2 = wb - 1024;
  const int side = wb2 / linPer;
  const float* x = side ? xl_ : xp;
  const int K = side ? Kl : Kp;
  const int N = side ? Nl : Np;
  const float* Wl = side ? W1ll : W1pl;
  const float* Wr = side ? W1lr : W1pr;
  u16* xlh = side ? xlh_l : xlh_p;
  u16* xrh = side ? xrh_l : xrh_p;
  int base = (wb2 - side * linPer) * 8;
  if (base >= N) return;
  int j = threadIdx.x;
  __shared__ float xs[16][8];  // [k][r] transposed for broadcast reads
  int tot = 8 * K;
  for (int i = j; i < tot; i += 256) {
    int r = i / K, k = i - r * K;
    if (base + r < N) xs[k][r] = x[(size_t)(base + r) * K + k];
  }
  __syncthreads();
  float al[8] = {}, ar[8] = {};
  for (int k = 0; k < K; ++k) {
    float wl = Wl[k * 256 + j];
    float wr = Wr[k * 256 + j];
#pragma unroll
    for (int r = 0; r < 8; ++r) {
      al[r] = fmaf(xs[k][r], wl, al[r]);
      ar[r] = fmaf(xs[k][r], wr, ar[r]);
    }
  }
#pragma unroll
  for (int r = 0; r < 8; ++r) {
    int n = base + r;
    if (n < N) {
      xlh[(size_t)n * 256 + j] = f2bf(al[r]);
      xrh[(size_t)n * 256 + j] = f2bf(ar[r]);
    }
  }
}

// ---------------- histogram (both sides) ----------------
__global__ void k_histb(const int* __restrict__ eip, int Ep, const int* __restrict__ eil,
                        int El, int* __restrict__ cntp, int* __restrict__ cntl) {
  int e = blockIdx.x * blockDim.x + threadIdx.x;
  if (e < Ep) atomicAdd(&cntp[eip[Ep + e]], 1);
  else if (e < Ep + El) { int e2 = e - Ep; atomicAdd(&cntl[eil[El + e2]], 1); }
}

// ---------------- per-block scan (also zeroes cur) ----------------
__global__ void k_scan1b(const int* __restrict__ cntp, int Np, const int* __restrict__ cntl,
                         int Nl, int nbp, int* __restrict__ offsp, int* __restrict__ offsl,
                         int* __restrict__ curp, int* __restrict__ curl,
                         int* __restrict__ bsum) {
  __shared__ int s[256];
  int tid = threadIdx.x;
  int side = ((int)blockIdx.x >= nbp) ? 1 : 0;
  int blk = side ? (blockIdx.x - nbp) : blockIdx.x;
  const int* cnt = side ? cntl : cntp;
  int* offs = side ? offsl : offsp;
  int* cur = side ? curl : curp;
  int N = side ? Nl : Np;
  int i = blk * 256 + tid;
  int v = (i < N) ? cnt[i] : 0;
  if (i < N) cur[i] = 0;
  s[tid] = v;
  __syncthreads();
  for (int off = 1; off < 256; off <<= 1) {
    int t = 0;
    if (tid >= off) t = s[tid - off];
    __syncthreads();
    if (tid >= off) s[tid] += t;
    __syncthreads();
  }
  if (i < N) offs[i] = s[tid] - v;
  if (tid == 255) bsum[side * 256 + blk] = s[255];
}

__global__ void k_scan2b(int* __restrict__ bsum, int nbp, int nbl) {
  __shared__ int s[256];
  int side = blockIdx.x;
  int nb = side ? nbl : nbp;
  int* bs = bsum + side * 256;
  int tid = threadIdx.x;
  int v = (tid < nb) ? bs[tid] : 0;
  s[tid] = v;
  __syncthreads();
  for (int off = 1; off < 256; off <<= 1) {
    int t = 0;
    if (tid >= off) t = s[tid - off];
    __syncthreads();
    if (tid >= off) s[tid] += t;
    __syncthreads();
  }
  if (tid < nb) bs[tid] = s[tid] - v;
}

// ---------------- fill (bsum folded in) ----------------
__global__ void k_fillb(const int* __restrict__ eip, int Ep, const int* __restrict__ eil,
                        int El, const int* __restrict__ offsp, const int* __restrict__ offsl,
                        const int* __restrict__ bsum,
                        int* __restrict__ curp, int* __restrict__ curl,
                        int* __restrict__ csrp, int* __restrict__ csrl) {
  int e = blockIdx.x * blockDim.x + threadIdx.x;
  if (e < Ep) {
    int d = eip[Ep + e];
    int pos = offsp[d] + bsum[d >> 8] + atomicAdd(&curp[d], 1);
    csrp[pos] = eip[e];
  } else if (e < Ep + El) {
    int e2 = e - Ep;
    int d = eil[El + e2];
    int pos = offsl[d] + bsum[256 + (d >> 8)] + atomicAdd(&curl[d], 1);
    csrl[pos] = eil[e2];
  }
}

// ---------------- dual GEMM, 128x128 y=4 proven shape; XCD-grouped block swizzle ----------------
// NOTE: 128x256-wide tile regressed 2x with ~3.6x HBM write amplification (rounds 6, 11).
__global__ void __launch_bounds__(256, 2) k_mm_dual_b(
    const u16* __restrict__ A_p, const u16* __restrict__ A_l,
    const u16* __restrict__ Bh_p, const u16* __restrict__ Bl_p,
    const u16* __restrict__ Bh_l, const u16* __restrict__ Bl_l,
    u16* __restrict__ XLh_p, u16* __restrict__ XRh_p,
    u16* __restrict__ XLh_l, u16* __restrict__ XRh_l, int Np, int Nl, int Rp, int Rtot) {
  __shared__ __align__(16) char smem[32768];
  char* sA = smem;
  char* sBh = smem + 8192;
  char* sBl = smem + 16384;
  const int gid = blockIdx.x;
  const int rblk = (gid >> 5) * 8 + (gid & 7);
  const int col = (gid >> 3) & 3;
  if (rblk >= Rtot) return;
  const int side = (rblk >= Rp) ? 1 : 0;
  const int rloc = side ? rblk - Rp : rblk;
  const u16* A = side ? A_l : A_p;
  const u16* Bhi = side ? Bh_l : Bh_p;
  const u16* Blo = side ? Bl_l : Bl_p;
  u16* XLh = side ? XLh_l : XLh_p;
  u16* XRh = side ? XRh_l : XRh_p;
  const int M = side ? Nl : Np;
  const int t = threadIdx.x;
  const int rowBase = rloc * 128;
  const int j0 = col * 128;
  const int srow = t >> 1;
  const int h = t & 1;
  int gr = rowBase + srow;
  if (gr >= M) gr = M - 1;
  const size_t gaBase = (size_t)gr * 256 + h * 16;
  const size_t gbBase = (size_t)(j0 + srow) * 256 + h * 16;
  const int rb = srow * 64;
  const int sw0 = (((h * 2) + (srow >> 1)) & 3) * 16;
  const int sw1 = (((h * 2 + 1) + (srow >> 1)) & 3) * 16;
  const int lane = t & 63;
  const int wid = t >> 6;
  const int wm = (wid & 1) * 64;
  const int wn = (wid >> 1) * 64;
  const int kq = lane >> 4;
  const int mr = lane & 15;
  int offA[4], offB[4];
#pragma unroll
  for (int i = 0; i < 4; ++i) {
    int m = wm + i * 16 + mr;
    offA[i] = m * 64 + ((kq + (m >> 1)) & 3) * 16;
    int n = wn + i * 16 + mr;
    offB[i] = n * 64 + ((kq + (n >> 1)) & 3) * 16;
  }
  f32x4 acc[4][4] = {};
  for (int kt = 0; kt < 8; ++kt) {
    const int k0 = kt * 32;
    uint4 va0 = *(const uint4*)(A + gaBase + k0);
    uint4 va1 = *(const uint4*)(A + gaBase + k0 + 8);
    uint4 vbh0 = *(const uint4*)(Bhi + gbBase + k0);
    uint4 vbh1 = *(const uint4*)(Bhi + gbBase + k0 + 8);
    uint4 vbl0 = *(const uint4*)(Blo + gbBase + k0);
    uint4 vbl1 = *(const uint4*)(Blo + gbBase + k0 + 8);
    __syncthreads();
    *(uint4*)(sA + rb + sw0) = va0;
    *(uint4*)(sA + rb + sw1) = va1;
    *(uint4*)(sBh + rb + sw0) = vbh0;
    *(uint4*)(sBh + rb + sw1) = vbh1;
    *(uint4*)(sBl + rb + sw0) = vbl0;
    *(uint4*)(sBl + rb + sw1) = vbl1;
    __syncthreads();
    bf16x8 a[4], bh[4], bl[4];
#pragma unroll
    for (int i = 0; i < 4; ++i) {
      a[i] = *(const bf16x8*)(sA + offA[i]);
      bh[i] = *(const bf16x8*)(sBh + offB[i]);
      bl[i] = *(const bf16x8*)(sBl + offB[i]);
    }
#pragma unroll
    for (int i = 0; i < 4; ++i)
#pragma unroll
      for (int j = 0; j < 4; ++j) {
        acc[i][j] = __builtin_amdgcn_mfma_f32_16x16x32_bf16(a[i], bh[j], acc[i][j], 0, 0, 0);
        acc[i][j] = __builtin_amdgcn_mfma_f32_16x16x32_bf16(a[i], bl[j], acc[i][j], 0, 0, 0);
      }
  }
  __syncthreads();
  u16* wtile = (u16*)(smem + wid * 8192);
#pragma unroll
  for (int i = 0; i < 4; ++i)
#pragma unroll
    for (int j = 0; j < 4; ++j)
#pragma unroll
      for (int r = 0; r < 4; ++r)
        wtile[(i * 16 + kq * 4 + r) * 64 + j * 16 + mr] = f2bf(acc[i][j][r]);
  u16* cbase = (col < 2) ? XLh : XRh;
  const int cb = (col < 2) ? j0 : j0 - 256;
  const int r8 = lane >> 3;
  const int c8 = lane & 7;
#pragma unroll
  for (int rr = 0; rr < 8; ++rr) {
    int lr = rr * 8 + r8;
    uint4 v = *(const uint4*)&wtile[lr * 64 + c8 * 8];
    int row = rowBase + wm + lr;
    if (row < M) *(uint4*)&cbase[(size_t)row * 256 + cb + wn + c8 * 8] = v;
  }
}

// ---------------- GATv2 aggregation (round-14 proven: full wave, 4-acc, NO index prefetch) ----------------
// lrelu(t)*wa == t*(0.6wa) + |t|*(0.4wa) exactly; softmax shift fixed at self logit.
// NOTE: half-wave variant regressed (round 13: halves loads-in-flight); clamped csr
// prefetch regressed (round 15: +4 VGPR, occupancy 61->54%). Keep this exact form.
#define GAT_DOT(a, q)                                                          \
  {                                                                            \
    float t0 = a.x + rd.x, t1 = a.y + rd.y, t2 = a.z + rd.z, t3 = a.w + rd.w;  \
    q = fmaf(t3, wa6.w, fabsf(t3) * wa4.w);                                    \
    q = fmaf(fabsf(t2), wa4.z, fmaf(t2, wa6.z, q));                            \
    q = fmaf(fabsf(t1), wa4.y, fmaf(t1, wa6.y, q));                            \
    q = fmaf(fabsf(t0), wa4.x, fmaf(t0, wa6.x, q));                            \
  }

template <int H>
__global__ void k_gat_gather_b(
    const u16* __restrict__ xlh_p, const u16* __restrict__ xrh_p, u16* __restrict__ out_p,
    const u16* __restrict__ xlh_l, const u16* __restrict__ xrh_l, u16* __restrict__ out_l,
    const int* __restrict__ csr_p, const int* __restrict__ offs_p,
    const int* __restrict__ cnt_p,
    const int* __restrict__ csr_l, const int* __restrict__ offs_l,
    const int* __restrict__ cnt_l, const int* __restrict__ bsum,
    const float* __restrict__ att_p, const float* __restrict__ bias_p,
    const float* __restrict__ att_l, const float* __restrict__ bias_l,
    int Np, int Nl) {
  const int side = blockIdx.y;
  const u16* xlh = side ? xlh_l : xlh_p;
  const u16* xrh = side ? xrh_l : xrh_p;
  u16* out = side ? out_l : out_p;
  const int* csr = side ? csr_l : csr_p;
  const int* offs = side ? offs_l : offs_p;
  const int* cnt = side ? cnt_l : cnt_p;
  const float* att = side ? att_l : att_p;
  const float* bias = side ? bias_l : bias_p;
  const int N = side ? Nl : Np;
  int d = blockIdx.x * 4 + (threadIdx.x >> 6);
  if (d >= N) return;
  const int lo4 = (threadIdx.x & 63) * 4;
  const float4 rd = ld_bf4(&xrh[(size_t)d * 256 + lo4]);
  const float4 wa = *(const float4*)&att[lo4];
  const float4 wa6 = make_float4(0.6f * wa.x, 0.6f * wa.y, 0.6f * wa.z, 0.6f * wa.w);
  const float4 wa4 = make_float4(0.4f * wa.x, 0.4f * wa.y, 0.4f * wa.z, 0.4f * wa.w);
  const float4 xd = ld_bf4(&xlh[(size_t)d * 256 + lo4]);
  float base;
  GAT_DOT(xd, base)
#pragma unroll
  for (int off = 1; off <= (H == 2 ? 16 : 32); off <<= 1) base += __shfl_xor(base, off, 64);
  float l0 = 1.f, l1 = 0.f, l2 = 0.f, l3 = 0.f;
  float4 acc0 = xd;
  float4 acc1 = make_float4(0.f, 0.f, 0.f, 0.f);
  float4 acc2 = make_float4(0.f, 0.f, 0.f, 0.f);
  float4 acc3 = make_float4(0.f, 0.f, 0.f, 0.f);
  const int o0 = offs[d] + bsum[side * 256 + (d >> 8)];
  const int c = cnt[d];
  int j = 0;
  for (; j + 3 < c; j += 4) {
    int s0 = csr[o0 + j], s1 = csr[o0 + j + 1], s2 = csr[o0 + j + 2], s3 = csr[o0 + j + 3];
    float4 a0 = ld_bf4(&xlh[(size_t)s0 * 256 + lo4]);
    float4 a1 = ld_bf4(&xlh[(size_t)s1 * 256 + lo4]);
    float4 a2 = ld_bf4(&xlh[(size_t)s2 * 256 + lo4]);
    float4 a3 = ld_bf4(&xlh[(size_t)s3 * 256 + lo4]);
    float q0, q1, q2, q3;
    GAT_DOT(a0, q0)
    GAT_DOT(a1, q1)
    GAT_DOT(a2, q2)
    GAT_DOT(a3, q3)
#pragma unroll
    for (int off = 1; off <= (H == 2 ? 16 : 32); off <<= 1) {
      q0 += __shfl_xor(q0, off, 64);
      q1 += __shfl_xor(q1, off, 64);
      q2 += __shfl_xor(q2, off, 64);
      q3 += __shfl_xor(q3, off, 64);
    }
    float w0 = __expf(q0 - base), w1 = __expf(q1 - base);
    float w2 = __expf(q2 - base), w3 = __expf(q3 - base);
    l0 += w0; l1 += w1; l2 += w2; l3 += w3;
    acc0.x = fmaf(w0, a0.x, acc0.x); acc0.y = fmaf(w0, a0.y, acc0.y);
    acc0.z = fmaf(w0, a0.z, acc0.z); acc0.w = fmaf(w0, a0.w, acc0.w);
    acc1.x = fmaf(w1, a1.x, acc1.x); acc1.y = fmaf(w1, a1.y, acc1.y);
    acc1.z = fmaf(w1, a1.z, acc1.z); acc1.w = fmaf(w1, a1.w, acc1.w);
    acc2.x = fmaf(w2, a2.x, acc2.x); acc2.y = fmaf(w2, a2.y, acc2.y);
    acc2.z = fmaf(w2, a2.z, acc2.z); acc2.w = fmaf(w2, a2.w, acc2.w);
    acc3.x = fmaf(w3, a3.x, acc3.x); acc3.y = fmaf(w3, a3.y, acc3.y);
    acc3.z = fmaf(w3, a3.z, acc3.z); acc3.w = fmaf(w3, a3.w, acc3.w);
  }
  for (; j < c; ++j) {
    int s0 = csr[o0 + j];
    float4 a0 = ld_bf4(&xlh[(size_t)s0 * 256 + lo4]);
    float q0;
    GAT_DOT(a0, q0)
#pragma unroll
    for (int off = 1; off <= (H == 2 ? 16 : 32); off <<= 1) q0 += __shfl_xor(q0, off, 64);
    float w0 = __expf(q0 - base);
    l0 += w0;
    acc0.x = fmaf(w0, a0.x, acc0.x); acc0.y = fmaf(w0, a0.y, acc0.y);
    acc0.z = fmaf(w0, a0.z, acc0.z); acc0.w = fmaf(w0, a0.w, acc0.w);
  }
  float inv = 1.f / (l0 + l1 + l2 + l3);
  float ax = acc0.x + acc1.x + acc2.x + acc3.x;
  float ay = acc0.y + acc1.y + acc2.y + acc3.y;
  float az = acc0.z + acc1.z + acc2.z + acc3.z;
  float aw = acc0.w + acc1.w + acc2.w + acc3.w;
  const float4 b4 = *(const float4*)&bias[lo4];
  ushort4 hv;
  hv.x = f2bf(ax * inv + b4.x);
  hv.y = f2bf(ay * inv + b4.y);
  hv.z = f2bf(az * inv + b4.z);
  hv.w = f2bf(aw * inv + b4.w);
  *(ushort4*)&out[(size_t)d * 256 + lo4] = hv;
}

// ---------------- chunked partial pool: grid (B, 2 sides, C chunks) ----------------
#define POOL_C 8
__global__ void k_pool_part(const u16* __restrict__ xp, const int* __restrict__ bp, int Np,
                            const u16* __restrict__ xl_, const int* __restrict__ bl_, int Nl,
                            float* __restrict__ PPpart, float* __restrict__ LPpart) {
  const int b = blockIdx.x;
  const int side = blockIdx.y;
  const int chunk = blockIdx.z;
  const u16* x = side ? xl_ : xp;
  const int* batch = side ? bl_ : bp;
  const int N = side ? Nl : Np;
  float* part = side ? LPpart : PPpart;
  int j = threadIdx.x;
  __shared__ int sss, sse;
  if (j == 0) {
    int lo = 0, hi = N;
    while (lo < hi) { int mid = (lo + hi) >> 1; if (batch[mid] < b) lo = mid + 1; else hi = mid; }
    sss = lo;
    lo = 0; hi = N;
    while (lo < hi) { int mid = (lo + hi) >> 1; if (batch[mid] < b + 1) lo = mid + 1; else hi = mid; }
    sse = lo;
  }
  __syncthreads();
  int len = sse - sss;
  int per = (len + POOL_C - 1) / POOL_C;
  int st = sss + chunk * per;
  int en = st + per;
  if (en > sse) en = sse;
  float acc = 0.f;
  for (int n = st; n < en; ++n) acc += bf2f(x[(size_t)n * 256 + j]);
  part[((size_t)chunk * 256 + b) * 256 + j] = acc;
}

// ---------------- head ----------------
__global__ void k_head(const float* __restrict__ PPpart, const float* __restrict__ LPpart,
                       const int* __restrict__ bp, int Np,
                       const int* __restrict__ bl_, int Nl,
                       const float* __restrict__ Wv, const float* __restrict__ bv,
                       const float* __restrict__ Wo, const float* __restrict__ bo,
                       const float* __restrict__ fc1w, const float* __restrict__ fc1b,
                       const float* __restrict__ lng, const float* __restrict__ lnb,
                       const float* __restrict__ fc2w, const float* __restrict__ fc2b,
                       float* __restrict__ out) {
  int b = blockIdx.x;
  int j = threadIdx.x;
  __shared__ float lxs[256];
  __shared__ float vbuf[256];
  __shared__ float comb[512];
  __shared__ float r1[256], r2[256];
  __shared__ float smu, srs;
  __shared__ int seg[4];
  if (j < 2) {
    const int* batch = j ? bl_ : bp;
    int N = j ? Nl : Np;
    int lo = 0, hi = N;
    while (lo < hi) { int mid = (lo + hi) >> 1; if (batch[mid] < b) lo = mid + 1; else hi = mid; }
    seg[j * 2] = lo;
    lo = 0; hi = N;
    while (lo < hi) { int mid = (lo + hi) >> 1; if (batch[mid] < b + 1) lo = mid + 1; else hi = mid; }
    seg[j * 2 + 1] = lo;
  }
  __syncthreads();
  {
    float accp = 0.f, accl = 0.f;
#pragma unroll
    for (int c = 0; c < POOL_C; ++c) {
      accp += PPpart[((size_t)c * 256 + b) * 256 + j];
      accl += LPpart[((size_t)c * 256 + b) * 256 + j];
    }
    comb[j] = accp / fmaxf((float)(seg[1] - seg[0]), 1.f);
    lxs[j] = accl / fmaxf((float)(seg[3] - seg[2]), 1.f);
  }
  __syncthreads();
  float v = bv[j];
  for (int k = 0; k < 256; ++k) v = fmaf(lxs[k], Wv[k * 256 + j], v);
  vbuf[j] = v;
  __syncthreads();
  float at = bo[j];
  for (int k = 0; k < 256; ++k) at = fmaf(vbuf[k], Wo[k * 256 + j], at);
  comb[256 + j] = at;
  __syncthreads();
  float h = fc1b[j];
  for (int k = 0; k < 512; ++k) h = fmaf(comb[k], fc1w[k * 256 + j], h);
  r1[j] = h;
  r2[j] = h * h;
  __syncthreads();
  for (int off = 128; off > 0; off >>= 1) {
    if (j < off) { r1[j] += r1[j + off]; r2[j] += r2[j + off]; }
    __syncthreads();
  }
  if (j == 0) {
    float mu = r1[0] / 256.f;
    float var = r2[0] / 256.f - mu * mu;
    smu = mu;
    srs = 1.f / sqrtf(var + 1e-5f);
  }
  __syncthreads();
  float hn = (h - smu) * srs * lng[j] + lnb[j];
  hn = hn > 0.f ? hn : 0.01f * hn;
  r1[j] = hn * fc2w[j];
  __syncthreads();
  for (int off = 128; off > 0; off >>= 1) {
    if (j < off) r1[j] += r1[j + off];
    __syncthreads();
  }
  if (j == 0) out[b] = r1[0] + fc2b[0];
}

extern "C" void kernel_launch(void* const* d_in, const int* in_sizes, int n_in,
                              void* d_out, int out_size, void* d_ws, size_t ws_size,
                              hipStream_t stream) {
  const float* px = (const float*)d_in[0];
  const float* lx = (const float*)d_in[1];
  const int* pei = (const int*)d_in[2];
  const int* lei = (const int*)d_in[3];
  const int* pb = (const int*)d_in[4];
  const int* lb = (const int*)d_in[5];
  const float* p1_Wl = (const float*)d_in[6];
  const float* p1_Wr = (const float*)d_in[7];
  const float* p1_att = (const float*)d_in[8];
  const float* p1_b = (const float*)d_in[9];
  const float* p2_Wl = (const float*)d_in[10];
  const float* p2_Wr = (const float*)d_in[11];
  const float* p2_att = (const float*)d_in[12];
  const float* p2_b = (const float*)d_in[13];
  const float* l1_Wl = (const float*)d_in[14];
  const float* l1_Wr = (const float*)d_in[15];
  const float* l1_att = (const float*)d_in[16];
  const float* l1_b = (const float*)d_in[17];
  const float* l2_Wl = (const float*)d_in[18];
  const float* l2_Wr = (const float*)d_in[19];
  const float* l2_att = (const float*)d_in[20];
  const float* l2_b = (const float*)d_in[21];
  const float* Wv = (const float*)d_in[26];
  const float* bv = (const float*)d_in[27];
  const float* Wo = (const float*)d_in[28];
  const float* bo = (const float*)d_in[29];
  const float* fc1w = (const float*)d_in[30];
  const float* fc1b = (const float*)d_in[31];
  const float* lng = (const float*)d_in[32];
  const float* lnb = (const float*)d_in[33];
  const float* fc2w = (const float*)d_in[34];
  const float* fc2b = (const float*)d_in[35];

  const int NPn = in_sizes[4];
  const int NLn = in_sizes[5];
  const int EPe = in_sizes[2] / 2;
  const int ELe = in_sizes[3] / 2;
  const int KP = in_sizes[0] / NPn;
  const int KL = in_sizes[1] / NLn;

  const int Nmax = NPn > NLn ? NPn : NLn;
  const int Emax = EPe > ELe ? EPe : ELe;
  size_t NF = (size_t)Nmax * 256;

  u16* XLh_p = (u16*)d_ws;
  u16* XRh_p = XLh_p + NF;
  u16* Ah_p = XRh_p + NF;
  u16* XLh_l = Ah_p + NF;
  u16* XRh_l = XLh_l + NF;
  u16* Ah_l = XRh_l + NF;
  u16* Wth = Ah_l + NF;  // 2 sides x 512*256
  u16* Wtl = Wth + 2 * 512 * 256;
  float* PPpart = (float*)(Wtl + 2 * 512 * 256);  // POOL_C x 256 x 256
  float* LPpart = PPpart + (size_t)POOL_C * 256 * 256;
  int* cnt = (int*)(LPpart + (size_t)POOL_C * 256 * 256);
  int* cur = cnt + 2 * (size_t)Nmax;
  int* offs = cur + 2 * (size_t)Nmax;
  int* bsum = offs + 2 * (size_t)Nmax;
  int* csr = bsum + 512;
  int* cnt_l = cnt + Nmax;
  int* cur_l = cur + Nmax;
  int* offs_l = offs + Nmax;
  int* csr_l = csr + Emax;

  const int nbp = (NPn + 255) / 256;
  const int nbl = (NLn + 255) / 256;
  const int nz = 2 * Nmax;
  const int zb = (nz + 255) / 256;
  const int linPer = (Nmax + 7) / 8;

  // setup: zero cnt + weight split + layer-1 linear (fused)
  k_setup<<<zb + 1024 + 2 * linPer, 256, 0, stream>>>(
      cnt, nz, p2_Wl, p2_Wr, l2_Wl, l2_Wr,
      Wth, Wtl, Wth + 512 * 256, Wtl + 512 * 256,
      px, KP, NPn, lx, KL, NLn, p1_Wl, p1_Wr, l1_Wl, l1_Wr,
      XLh_p, XRh_p, XLh_l, XRh_l, linPer);
  // CSR build
  k_histb<<<(EPe + ELe + 255) / 256, 256, 0, stream>>>(pei, EPe, lei, ELe, cnt, cnt_l);
  k_scan1b<<<nbp + nbl, 256, 0, stream>>>(cnt, NPn, cnt_l, NLn, nbp, offs, offs_l,
                                          cur, cur_l, bsum);
  k_scan2b<<<2, 256, 0, stream>>>(bsum, nbp, nbl);
  k_fillb<<<(EPe + ELe + 255) / 256, 256, 0, stream>>>(pei, EPe, lei, ELe, offs, offs_l,
                                                       bsum, cur, cur_l, csr, csr_l);
  // layer 1 gather
  k_gat_gather_b<2><<<dim3((Nmax + 3) / 4, 2), 256, 0, stream>>>(
      XLh_p, XRh_p, Ah_p, XLh_l, XRh_l, Ah_l,
      csr, offs, cnt, csr_l, offs_l, cnt_l, bsum,
      p1_att, p1_b, l1_att, l1_b, NPn, NLn);
  // layer 2 GEMM (XCD-grouped swizzle)
  {
    const int Rp = (NPn + 127) / 128;
    const int Rl = (NLn + 127) / 128;
    const int Rtot = Rp + Rl;
    k_mm_dual_b<<<32 * ((Rtot + 7) / 8), 256, 0, stream>>>(
        Ah_p, Ah_l, Wth, Wtl, Wth + 512 * 256, Wtl + 512 * 256,
        XLh_p, XRh_p, XLh_l, XRh_l, NPn, NLn, Rp, Rtot);
  }
  k_gat_gather_b<1><<<dim3((Nmax + 3) / 4, 2), 256, 0, stream>>>(
      XLh_p, XRh_p, Ah_p, XLh_l, XRh_l, Ah_l,
      csr, offs, cnt, csr_l, offs_l, cnt_l, bsum,
      p2_att, p2_b, l2_att, l2_b, NPn, NLn);
  // pool (chunked partials) + head
  k_pool_part<<<dim3(256, 2, POOL_C), 256, 0, stream>>>(Ah_p, pb, NPn, Ah_l, lb, NLn,
                                                        PPpart, LPpart);
  k_head<<<256, 256, 0, stream>>>(PPpart, LPpart, pb, NPn, lb, NLn,
                                  Wv, bv, Wo, bo, fc1w, fc1b, lng, lnb, fc2w, fc2b,
                                  (float*)d_out);
  (void)n_in; (void)out_size; (void)ws_size;
}